// Round 2
// baseline (992.417 us; speedup 1.0000x reference)
//
#include <hip/hip_runtime.h>

// ---------------------------------------------------------------------------
// PraxisBlock: rmsnorm -> QKV -> causal MHA -> O+residual -> rmsnorm ->
//              router top2/8 -> gathered expert FFN (gelu) -> combine
// All GEMMs: fp16 MFMA (v_mfma_f32_16x16x32_f16), fp32 accumulate.
// R1: router restructured — no global atomics (was 515us of XCD ping-pong).
// R2: attention re-tiled 64 q-rows/block, 1024 blocks, 32KB LDS.
// R3: XOR-swizzled LDS in gemm128 + split-K x2 for moe2.
// R4 (REVERTED): moe1 at 256x256/128KB LDS forced 1 block/CU, killed the
//     cross-block overlap that was hiding the barrier drain (194us, MfmaUtil
//     17% vs 21%). Lesson: 2-phase prefetch needs >=2 blocks/CU co-resident.
// R5: gemm128 core double-buffered (64KB LDS, still 2 blocks/CU): stage
//     K-tile t+1 into buf^1 while MFMAing tile t, ONE barrier per K-tile
//     (was stage/barrier/compute with two barriers). Applied to qkv, o,
//     moe1 (back at 128^2, grid (32,32,8)), moe2. Target: m228d quadrant
//     128^2+2ph ~= 622 TF vs current 470.
// ---------------------------------------------------------------------------

typedef _Float16 f16;
typedef _Float16 f16x8 __attribute__((ext_vector_type(8)));
typedef _Float16 f16x4v __attribute__((ext_vector_type(4)));
typedef float f32x4 __attribute__((ext_vector_type(4)));

#define DMODEL 1024
#define NHEAD  16
#define HDIM   64
#define NEXP   8
#define DFFN   4096
#define NBATCH 2
#define NSEQ   2048
#define NTOK   4096   // NBATCH*NSEQ
#define NPAIR  8192   // NTOK*2

// ---- workspace byte offsets (all 256-aligned) ----
#define OFF_WQKVT  0ull                  // 3*1024*1024 f16
#define OFF_WOT    6291456ull            // 1024*1024 f16
#define OFF_W1T    8388608ull            // 8*4096*1024 f16
#define OFF_W2T    75497472ull           // 8*1024*4096 f16
#define OFF_HATTN  142606336ull          // 4096*1024 f16   (dead after gemm_o; y2 reuses)
#define OFF_Q      150994944ull          // 32*2048*64 f16
#define OFF_K      159383552ull
#define OFF_VT     167772160ull
#define OFF_OC     176160768ull          // 4096*1024 f16
#define OFF_XMID   184549376ull          // 4096*1024 f32
#define OFF_HMLP   201326592ull          // 4096*1024 f16
#define OFF_HID    209715200ull          // 8192*4096 f16
#define OFF_Y      276824064ull          // 8192*1024 f32 (split-K half 0, +bias)
#define OFF_Y2     OFF_HATTN             // 8192*1024 f32 (split-K half 1) — hattn/q/k/vt dead by then
#define OFF_LIST   310378496ull          // 8*4096 int
#define OFF_METAE  310509568ull          // 4096 int2
#define OFF_METAP  310542336ull          // 4096 int2
#define OFF_METAS  310575104ull          // 4096 float2
#define OFF_BPSUM  310607872ull          // 1024*8 float (per-block prob sums)
#define OFF_CNT    310640640ull          // 8 int
#define OFF_PSUM   310640704ull          // 8 float
#define OFF_BASE   310640768ull          // 9 int

__device__ __forceinline__ void ldsAsync16(const void* g, void* l) {
  __builtin_amdgcn_global_load_lds((const __attribute__((address_space(1))) void*)g,
                                   (__attribute__((address_space(3))) void*)l, 16, 0, 0);
}

// ---------------- transpose + cast fp32[R][C] -> fp16[C][R] ----------------
__global__ void transpose_cast_kernel(const float* __restrict__ src, f16* __restrict__ dst,
                                      int R, int C) {
  __shared__ float tile[32][33];
  const size_t zoff = (size_t)blockIdx.z * R * C;
  src += zoff; dst += zoff;
  int c0 = blockIdx.x * 32, r0 = blockIdx.y * 32;
  int tx = threadIdx.x, ty = threadIdx.y;
#pragma unroll
  for (int i = 0; i < 4; i++)
    tile[ty + i * 8][tx] = src[(size_t)(r0 + ty + i * 8) * C + c0 + tx];
  __syncthreads();
#pragma unroll
  for (int i = 0; i < 4; i++)
    dst[(size_t)(c0 + ty + i * 8) * R + r0 + tx] = (f16)tile[tx][ty + i * 8];
}

// ---------------- rmsnorm fp32 -> fp16 ----------------
__global__ void rmsnorm_kernel(const float* __restrict__ x, const float* __restrict__ w,
                               f16* __restrict__ out) {
  int t = blockIdx.x, tid = threadIdx.x;
  float4 v = ((const float4*)(x + (size_t)t * DMODEL))[tid];
  float ss = v.x * v.x + v.y * v.y + v.z * v.z + v.w * v.w;
#pragma unroll
  for (int o = 32; o > 0; o >>= 1) ss += __shfl_down(ss, o);
  __shared__ float red[4];
  if ((tid & 63) == 0) red[tid >> 6] = ss;
  __syncthreads();
  float tot = red[0] + red[1] + red[2] + red[3];
  float rstd = rsqrtf(tot / (float)DMODEL + 1e-6f);
  float4 wv = ((const float4*)w)[tid];
  f16x4v o4;
  o4[0] = (f16)(v.x * rstd * wv.x);
  o4[1] = (f16)(v.y * rstd * wv.y);
  o4[2] = (f16)(v.z * rstd * wv.z);
  o4[3] = (f16)(v.w * rstd * wv.w);
  *(f16x4v*)(out + (size_t)t * DMODEL + tid * 4) = o4;
}

// ---------------- shared 128x128xK MFMA core (XOR-swizzled LDS) ----------
// R5: double-buffered 2-phase pipeline. Per K-tile: issue global_load_lds
// for tile t+1 into buf^1, ds_read+MFMA tile t from buf, ONE __syncthreads
// (its vmcnt(0)+lgkmcnt(0) drain covers prefetch landing AND read-before-
// overwrite). 64KB LDS -> still 2 blocks/CU, so the residual drain is
// covered by the co-resident block (the R4 lesson).
// Staging contract: callers must point lane (kc=lane&7, rs=lane>>3) at global
// column chunk (kc ^ rs)*8 of its row, NOT kc*8. LDS[row][c] then holds global
// chunk c^(row&7); fragment reads below un-swizzle with j^(row&7).
template <class EPI>
__device__ __forceinline__ void gemm128(const f16* aP0, const f16* aP1, const f16* aP2, const f16* aP3,
                                        const f16* bP0, const f16* bP1, const f16* bP2, const f16* bP3,
                                        int K, EPI epi) {
  __shared__ __align__(16) f16 sA[2][128 * 64];
  __shared__ __align__(16) f16 sB[2][128 * 64];
  const int tid = threadIdx.x;
  const int lane = tid & 63, wave = tid >> 6;
  const int wm = (wave >> 1) * 64, wn = (wave & 1) * 64;
  const int q4 = lane >> 4, l15 = lane & 15;
  const int sw = lane & 7;  // == l15 & 7 == row&7 for fragment rows
  const f16* aP[4] = {aP0, aP1, aP2, aP3};
  const f16* bP[4] = {bP0, bP1, bP2, bP3};
  f32x4 zero = {0.f, 0.f, 0.f, 0.f};
  f32x4 acc[4][4];
#pragma unroll
  for (int i = 0; i < 4; i++)
#pragma unroll
    for (int j = 0; j < 4; j++) acc[i][j] = zero;

  // prologue: stage K-tile 0 into buffer 0
#pragma unroll
  for (int i = 0; i < 4; i++) {
    ldsAsync16(aP[i], &sA[0][(i * 4 + wave) * 512]);
    ldsAsync16(bP[i], &sB[0][(i * 4 + wave) * 512]);
  }
  __syncthreads();

  int cur = 0;
  for (int k0 = 64; k0 <= K; k0 += 64) {
    if (k0 < K) {  // prefetch next K-tile into the other buffer
#pragma unroll
      for (int i = 0; i < 4; i++) {
        ldsAsync16(aP[i] + k0, &sA[cur ^ 1][(i * 4 + wave) * 512]);
        ldsAsync16(bP[i] + k0, &sB[cur ^ 1][(i * 4 + wave) * 512]);
      }
    }
#pragma unroll
    for (int kk = 0; kk < 2; kk++) {
      f16x8 af[4], bf[4];
      int jx = ((kk * 4 + q4) ^ sw) * 8;
#pragma unroll
      for (int mi = 0; mi < 4; mi++)
        af[mi] = *(const f16x8*)&sA[cur][(wm + mi * 16 + l15) * 64 + jx];
#pragma unroll
      for (int ni = 0; ni < 4; ni++)
        bf[ni] = *(const f16x8*)&sB[cur][(wn + ni * 16 + l15) * 64 + jx];
#pragma unroll
      for (int mi = 0; mi < 4; mi++)
#pragma unroll
        for (int ni = 0; ni < 4; ni++)
          acc[mi][ni] = __builtin_amdgcn_mfma_f32_16x16x32_f16(af[mi], bf[ni], acc[mi][ni], 0, 0, 0);
    }
    __syncthreads();  // reads of buf[cur] done + prefetch into buf[cur^1] landed
    cur ^= 1;
  }
#pragma unroll
  for (int mi = 0; mi < 4; mi++)
#pragma unroll
    for (int ni = 0; ni < 4; ni++)
#pragma unroll
      for (int r = 0; r < 4; r++)
        epi(wm + mi * 16 + q4 * 4 + r, wn + ni * 16 + l15, acc[mi][ni][r]);
}

// ---------------- QKV projection (N=3072 stacked) ----------------
__global__ __launch_bounds__(256, 2) void gemm_qkv_kernel(
    const f16* __restrict__ hA, const f16* __restrict__ wT,
    f16* __restrict__ qb, f16* __restrict__ kb, f16* __restrict__ vtb) {
  int mt = blockIdx.y, nt = blockIdx.x;
  int tid = threadIdx.x, lane = tid & 63, wave = tid >> 6;
  int kc = lane & 7, rs = lane >> 3;
  int kcs = (kc ^ rs) * 8;  // swizzled column chunk
  const f16 *a[4], *b[4];
#pragma unroll
  for (int i = 0; i < 4; i++) {
    int row = i * 32 + wave * 8 + rs;
    a[i] = hA + (size_t)(mt * 128 + row) * DMODEL + kcs;
    b[i] = wT + (size_t)(nt * 128 + row) * DMODEL + kcs;
  }
  int mB = mt * 128, nB = nt * 128;
  gemm128(a[0], a[1], a[2], a[3], b[0], b[1], b[2], b[3], DMODEL,
    [&](int r, int c, float v) {
      int m = mB + r, n = nB + c;
      int mat = n >> 10, nn = n & 1023;
      int h = nn >> 6, d = nn & 63;
      int bI = m >> 11, s = m & 2047;
      int bh = bI * NHEAD + h;
      f16 hv = (f16)v;
      if (mat == 0)      qb[((size_t)bh * NSEQ + s) * HDIM + d] = hv;
      else if (mat == 1) kb[((size_t)bh * NSEQ + s) * HDIM + d] = hv;
      else               vtb[((size_t)bh * HDIM + d) * NSEQ + s] = hv;
    });
}

// ---------------- O projection + residual ----------------
__global__ __launch_bounds__(256, 2) void gemm_o_kernel(
    const f16* __restrict__ oc, const f16* __restrict__ woT,
    const float* __restrict__ xin, float* __restrict__ xmid) {
  int mt = blockIdx.y, nt = blockIdx.x;
  int tid = threadIdx.x, lane = tid & 63, wave = tid >> 6;
  int kc = lane & 7, rs = lane >> 3;
  int kcs = (kc ^ rs) * 8;
  const f16 *a[4], *b[4];
#pragma unroll
  for (int i = 0; i < 4; i++) {
    int row = i * 32 + wave * 8 + rs;
    a[i] = oc + (size_t)(mt * 128 + row) * DMODEL + kcs;
    b[i] = woT + (size_t)(nt * 128 + row) * DMODEL + kcs;
  }
  int mB = mt * 128, nB = nt * 128;
  gemm128(a[0], a[1], a[2], a[3], b[0], b[1], b[2], b[3], DMODEL,
    [&](int r, int c, float v) {
      size_t idx = (size_t)(mB + r) * DMODEL + nB + c;
      xmid[idx] = xin[idx] + v;
    });
}

// ---------------- MoE expert GEMM 1: h -> gelu(h*w1+b1) ----------------
__global__ __launch_bounds__(256, 2) void gemm_moe1_kernel(
    const f16* __restrict__ hM, const f16* __restrict__ w1T, const float* __restrict__ b1,
    const int* __restrict__ cnt, const int* __restrict__ base, const int* __restrict__ list,
    f16* __restrict__ hid) {
  int e = blockIdx.z, mt = blockIdx.y, nt = blockIdx.x;
  int c_e = cnt[e];
  if (mt * 128 >= c_e) return;
  int tid = threadIdx.x, lane = tid & 63, wave = tid >> 6;
  int kc = lane & 7, rs = lane >> 3;
  int kcs = (kc ^ rs) * 8;
  const f16 *a[4], *b[4];
#pragma unroll
  for (int i = 0; i < 4; i++) {
    int row = i * 32 + wave * 8 + rs;
    int rr = mt * 128 + row; rr = rr < c_e ? rr : c_e - 1;
    int tok = list[e * NTOK + rr];
    a[i] = hM + (size_t)tok * DMODEL + kcs;
    b[i] = w1T + ((size_t)e * DFFN + nt * 128 + row) * DMODEL + kcs;
  }
  int rowBase = base[e] + mt * 128, nB = nt * 128, mLoc = mt * 128;
  gemm128(a[0], a[1], a[2], a[3], b[0], b[1], b[2], b[3], DMODEL,
    [&](int r, int c, float v) {
      if (mLoc + r < c_e) {
        float v2 = v + b1[e * DFFN + nB + c];
        float u = 1.5957691216057308f * (v2 + 0.044715f * v2 * v2 * v2); // 2*0.79788456*
        float th = 1.f - 2.f / (__expf(u) + 1.f);                        // tanh
        hid[(size_t)(rowBase + r) * DFFN + nB + c] = (f16)(0.5f * v2 * (1.f + th));
      }
    });
}

// ---------------- MoE expert GEMM 2: hid*w2+b2 -> y (split-K x2) ----------
__global__ __launch_bounds__(256, 2) void gemm_moe2_kernel(
    const f16* __restrict__ hid, const f16* __restrict__ w2T, const float* __restrict__ b2,
    const int* __restrict__ cnt, const int* __restrict__ base,
    float* __restrict__ y, float* __restrict__ y2) {
  int z = blockIdx.z, e = z >> 1, kh = z & 1;
  int mt = blockIdx.y, nt = blockIdx.x;
  int c_e = cnt[e];
  if (mt * 128 >= c_e) return;
  int tid = threadIdx.x, lane = tid & 63, wave = tid >> 6;
  int kc = lane & 7, rs = lane >> 3;
  int kcs = (kc ^ rs) * 8 + kh * 2048;
  int bse = base[e];
  const f16 *a[4], *b[4];
#pragma unroll
  for (int i = 0; i < 4; i++) {
    int row = i * 32 + wave * 8 + rs;
    int rr = mt * 128 + row; rr = rr < c_e ? rr : c_e - 1;
    a[i] = hid + (size_t)(bse + rr) * DFFN + kcs;
    b[i] = w2T + ((size_t)e * DMODEL + nt * 128 + row) * DFFN + kcs;
  }
  int nB = nt * 128, mLoc = mt * 128;
  float* yo = kh ? y2 : y;
  gemm128(a[0], a[1], a[2], a[3], b[0], b[1], b[2], b[3], 2048,
    [&](int r, int c, float v) {
      if (mLoc + r < c_e) {
        float bias = kh ? 0.f : b2[e * DMODEL + nB + c];
        yo[(size_t)(bse + mLoc + r) * DMODEL + nB + c] = v + bias;
      }
    });
}

// ---------------- flash attention (causal + key mask) ----------------
// 64 q-rows per block, 4 waves x 16 q-rows. bh on blockIdx.x so each head's
// K/V stays on one XCD (XCD = linear_id % 8 = bh % 8).
__global__ __launch_bounds__(256, 4) void attn_kernel(
    const f16* __restrict__ qb, const f16* __restrict__ kb, const f16* __restrict__ vtb,
    const int* __restrict__ amask, f16* __restrict__ oc) {
  int bh = blockIdx.x, qt = blockIdx.y;
  int bI = bh >> 4, h = bh & 15;
  int qbase = qt * 64;
  int tid = threadIdx.x, lane = tid & 63, wave = tid >> 6;
  int q4 = lane >> 4, l15 = lane & 15;
  int kc = lane & 7, rs = lane >> 3;

  __shared__ __align__(16) f16 sQ[64 * 64];
  __shared__ __align__(16) f16 sK[64 * 64];
  __shared__ __align__(16) f16 sVT[64 * 64];
  __shared__ __align__(16) f16 sP[4][16 * 64];
  __shared__ int sMask[64];

  const f16* qBH = qb + (size_t)bh * NSEQ * HDIM;
  const f16* kBH = kb + (size_t)bh * NSEQ * HDIM;
  const f16* vBH = vtb + (size_t)bh * HDIM * NSEQ;

#pragma unroll
  for (int i = 0; i < 2; i++) {
    int row = i * 32 + wave * 8 + rs;  // 0..63
    ldsAsync16(qBH + (size_t)(qbase + row) * HDIM + kc * 8, &sQ[(i * 4 + wave) * 512]);
  }

  f32x4 zero = {0.f, 0.f, 0.f, 0.f};
  f32x4 accO[4];
  float mrow[4], lrow[4];
#pragma unroll
  for (int j = 0; j < 4; j++) { accO[j] = zero; mrow[j] = -3.0e38f; lrow[j] = 0.f; }

  f16* sPw = sP[wave];

  for (int kt = 0; kt <= qt; kt++) {
    int kb0 = kt * 64;
    bool diag = (kt == qt);
    __syncthreads();
#pragma unroll
    for (int i = 0; i < 2; i++) {
      int row = i * 32 + wave * 8 + rs;  // 0..63
      ldsAsync16(kBH + (size_t)(kb0 + row) * HDIM + kc * 8, &sK[(i * 4 + wave) * 512]);
      ldsAsync16(vBH + (size_t)row * NSEQ + kb0 + kc * 8, &sVT[(i * 4 + wave) * 512]);
    }
    if (tid < 64) sMask[tid] = amask[bI * NSEQ + kb0 + tid];
    __syncthreads();

    f32x4 accS[4];
#pragma unroll
    for (int j = 0; j < 4; j++) accS[j] = zero;
#pragma unroll
    for (int kk = 0; kk < 2; kk++) {
      f16x8 af = *(const f16x8*)&sQ[(wave * 16 + l15) * 64 + kk * 32 + q4 * 8];
      f16x8 bf[4];
#pragma unroll
      for (int nj = 0; nj < 4; nj++)
        bf[nj] = *(const f16x8*)&sK[(nj * 16 + l15) * 64 + kk * 32 + q4 * 8];
#pragma unroll
      for (int nj = 0; nj < 4; nj++)
        accS[nj] = __builtin_amdgcn_mfma_f32_16x16x32_f16(af, bf[nj], accS[nj], 0, 0, 0);
    }
    bool mok[4];
    int gk[4];
#pragma unroll
    for (int nj = 0; nj < 4; nj++) {
      gk[nj] = nj * 16 + l15;
      mok[nj] = sMask[gk[nj]] > 0;
    }
#pragma unroll
    for (int r = 0; r < 4; r++) {
      int lq = wave * 16 + q4 * 4 + r;  // local q row 0..63; global gq = qbase+lq
      float rm = -3.0e38f;
#pragma unroll
      for (int nj = 0; nj < 4; nj++) {
        float s = accS[nj][r] * 0.125f;
        bool ok = mok[nj] && (!diag || gk[nj] <= lq);
        s = ok ? s : -1.0e9f;
        accS[nj][r] = s;
        rm = fmaxf(rm, s);
      }
#pragma unroll
      for (int o = 1; o < 16; o <<= 1) rm = fmaxf(rm, __shfl_xor(rm, o));
      float mold = mrow[r];
      float mnew = fmaxf(mold, rm);
      float alpha = __expf(mold - mnew);
      float rsum = 0.f;
#pragma unroll
      for (int nj = 0; nj < 4; nj++) {
        float p = __expf(accS[nj][r] - mnew);
        rsum += p;
        sPw[(q4 * 4 + r) * 64 + nj * 16 + l15] = (f16)p;
      }
#pragma unroll
      for (int o = 1; o < 16; o <<= 1) rsum += __shfl_xor(rsum, o);
      lrow[r] = lrow[r] * alpha + rsum;
      mrow[r] = mnew;
#pragma unroll
      for (int dj = 0; dj < 4; dj++) accO[dj][r] *= alpha;
    }
    // PV (sP is per-wave private; compiler's lgkmcnt covers write->read)
#pragma unroll
    for (int kk = 0; kk < 2; kk++) {
      f16x8 pf = *(const f16x8*)&sPw[l15 * 64 + kk * 32 + q4 * 8];
      f16x8 vf[4];
#pragma unroll
      for (int dj = 0; dj < 4; dj++)
        vf[dj] = *(const f16x8*)&sVT[(dj * 16 + l15) * 64 + kk * 32 + q4 * 8];
#pragma unroll
      for (int dj = 0; dj < 4; dj++)
        accO[dj] = __builtin_amdgcn_mfma_f32_16x16x32_f16(pf, vf[dj], accO[dj], 0, 0, 0);
    }
  }
  // epilogue: divide by l, scatter to o_concat[token][h*64+d]
#pragma unroll
  for (int r = 0; r < 4; r++) {
    float inv = 1.f / lrow[r];
    int s = qbase + wave * 16 + q4 * 4 + r;
    size_t rowoff = ((size_t)bI * NSEQ + s) * DMODEL + h * HDIM;
#pragma unroll
    for (int dj = 0; dj < 4; dj++)
      oc[rowoff + dj * 16 + l15] = (f16)(accO[dj][r] * inv);
  }
}

// ---------------- router: wave-per-token, NO global atomics ----------------
__global__ __launch_bounds__(256) void router_kernel(
    const float* __restrict__ xmid, const float* __restrict__ normw,
    const float* __restrict__ rw, int2* __restrict__ metaE,
    float2* __restrict__ metaS, float* __restrict__ blockpsum) {
  int wave = threadIdx.x >> 6, lane = threadIdx.x & 63;
  int t = blockIdx.x * 4 + wave;
  __shared__ float sprob[4][8];

  const float4* xr = (const float4*)(xmid + (size_t)t * DMODEL);
  const float4* wr = (const float4*)normw;
  float4 v[4];
  float ss = 0.f;
#pragma unroll
  for (int i = 0; i < 4; i++) {
    v[i] = xr[lane * 4 + i];
    ss += v[i].x * v[i].x + v[i].y * v[i].y + v[i].z * v[i].z + v[i].w * v[i].w;
  }
#pragma unroll
  for (int o = 32; o > 0; o >>= 1) ss += __shfl_xor(ss, o);
  float rstd = rsqrtf(ss / (float)DMODEL + 1e-6f);

  float part[8] = {0, 0, 0, 0, 0, 0, 0, 0};
#pragma unroll
  for (int i = 0; i < 4; i++) {
    float4 wv = wr[lane * 4 + i];
    float hv[4] = {v[i].x * rstd * wv.x, v[i].y * rstd * wv.y,
                   v[i].z * rstd * wv.z, v[i].w * rstd * wv.w};
#pragma unroll
    for (int j = 0; j < 4; j++) {
      int row = lane * 16 + i * 4 + j;
      const float4* rr = (const float4*)(rw + (size_t)row * NEXP);
      float4 a = rr[0], b = rr[1];
      part[0] += hv[j] * a.x; part[1] += hv[j] * a.y;
      part[2] += hv[j] * a.z; part[3] += hv[j] * a.w;
      part[4] += hv[j] * b.x; part[5] += hv[j] * b.y;
      part[6] += hv[j] * b.z; part[7] += hv[j] * b.w;
    }
  }
#pragma unroll
  for (int o = 1; o < 64; o <<= 1)
#pragma unroll
    for (int e = 0; e < 8; e++) part[e] += __shfl_xor(part[e], o);

  if (lane == 0) {
    float mx = -3.0e38f;
#pragma unroll
    for (int e = 0; e < 8; e++) mx = fmaxf(mx, part[e]);
    float probs[8], sum = 0.f;
#pragma unroll
    for (int e = 0; e < 8; e++) { probs[e] = __expf(part[e] - mx); sum += probs[e]; }
    float inv = 1.f / sum;
#pragma unroll
    for (int e = 0; e < 8; e++) { probs[e] *= inv; sprob[wave][e] = probs[e]; }
    int e0 = 0;
#pragma unroll
    for (int e = 1; e < 8; e++) if (part[e] > part[e0]) e0 = e;
    int e1 = (e0 == 0) ? 1 : 0;
#pragma unroll
    for (int e = 0; e < 8; e++) if (e != e0 && part[e] > part[e1]) e1 = e;
    metaE[t] = make_int2(e0, e1);
    metaS[t] = make_float2(probs[e0], probs[e1]);
  }
  __syncthreads();
  if (threadIdx.x < 8)
    blockpsum[blockIdx.x * 8 + threadIdx.x] =
        sprob[0][threadIdx.x] + sprob[1][threadIdx.x] +
        sprob[2][threadIdx.x] + sprob[3][threadIdx.x];
}

// ---------------- scatter: one block per expert, deterministic prefix sum ----
__global__ __launch_bounds__(256) void scatter_kernel(
    const int2* __restrict__ metaE, int* __restrict__ list,
    int* __restrict__ metaP, int* __restrict__ cnt) {
  int e = blockIdx.x;
  int tid = threadIdx.x, lane = tid & 63, w = tid >> 6;
  __shared__ int wsum[4];
  __shared__ int sbase;
  if (tid == 0) sbase = 0;
  __syncthreads();
  for (int c = 0; c < NTOK; c += 256) {
    int tok = c + tid;
    int2 me = metaE[tok];
    bool m0 = (me.x == e), m1 = (me.y == e);
    bool m = m0 || m1;
    unsigned long long mask = __ballot(m);
    int wpre = __popcll(mask & ((1ull << lane) - 1ull));
    if (lane == 0) wsum[w] = __popcll(mask);
    __syncthreads();
    int base0 = sbase;
    int pre = wpre;
    for (int i = 0; i < w; i++) pre += wsum[i];
    int tot = wsum[0] + wsum[1] + wsum[2] + wsum[3];
    if (m) {
      int pos = base0 + pre;
      list[e * NTOK + base0 + pre] = tok;
      metaP[tok * 2 + (m0 ? 0 : 1)] = pos;
    }
    __syncthreads();
    if (tid == 0) sbase = base0 + tot;
  }
  __syncthreads();
  if (tid == 0) cnt[e] = sbase;
}

// ---------------- finalize: base offsets + balancing loss + counts ----------
__global__ __launch_bounds__(256) void finalize_kernel(
    const int* __restrict__ cnt, const float* __restrict__ blockpsum,
    int* __restrict__ base, float* __restrict__ out_tail) {
  int tid = threadIdx.x;
  int e = tid & 7, slot = tid >> 3;  // 32 slots per expert
  float acc = 0.f;
  for (int i = slot; i < 1024; i += 32) acc += blockpsum[i * 8 + e];
  __shared__ float red[256];
  red[tid] = acc;
  __syncthreads();
  for (int s = 128; s >= 8; s >>= 1) {
    if (tid < s) red[tid] += red[tid + s];
    __syncthreads();
  }
  if (tid == 0) {
    int b = 0;
#pragma unroll
    for (int i = 0; i < 8; i++) { base[i] = b; b += cnt[i]; }
    base[8] = b;
    float loss = 0.f;
#pragma unroll
    for (int i = 0; i < 8; i++)
      loss += ((float)cnt[i] / (float)NPAIR) * (red[i] / (float)NTOK);
    out_tail[0] = loss * (float)NEXP;
#pragma unroll
    for (int i = 0; i < 8; i++) out_tail[1 + i] = (float)cnt[i];
  }
}

// ---------------- final combine (sums split-K halves) ----------------
__global__ void combine_kernel(const float* __restrict__ xmid, const float* __restrict__ yv,
                               const float* __restrict__ yv2,
                               const int2* __restrict__ metaE, const int* __restrict__ metaP,
                               const float2* __restrict__ metaS,
                               const int* __restrict__ base, float* __restrict__ out) {
  int t = blockIdx.x, tid = threadIdx.x;
  int2 me = metaE[t];
  float2 sc = metaS[t];
  size_t s0 = (size_t)(base[me.x] + metaP[t * 2 + 0]) * DMODEL;
  size_t s1 = (size_t)(base[me.y] + metaP[t * 2 + 1]) * DMODEL;
  float4 a = ((const float4*)(xmid + (size_t)t * DMODEL))[tid];
  float4 y0a = ((const float4*)(yv + s0))[tid];
  float4 y0b = ((const float4*)(yv2 + s0))[tid];
  float4 y1a = ((const float4*)(yv + s1))[tid];
  float4 y1b = ((const float4*)(yv2 + s1))[tid];
  float4 o;
  o.x = a.x + sc.x * (y0a.x + y0b.x) + sc.y * (y1a.x + y1b.x);
  o.y = a.y + sc.x * (y0a.y + y0b.y) + sc.y * (y1a.y + y1b.y);
  o.z = a.z + sc.x * (y0a.z + y0b.z) + sc.y * (y1a.z + y1b.z);
  o.w = a.w + sc.x * (y0a.w + y0b.w) + sc.y * (y1a.w + y1b.w);
  ((float4*)(out + (size_t)t * DMODEL))[tid] = o;
}

// ---------------------------------------------------------------------------
extern "C" void kernel_launch(void* const* d_in, const int* in_sizes, int n_in,
                              void* d_out, int out_size, void* d_ws, size_t ws_size,
                              hipStream_t stream) {
  (void)in_sizes; (void)n_in; (void)out_size; (void)ws_size;
  const float* x    = (const float*)d_in[0];
  const int*   am   = (const int*)d_in[1];
  const float* anw  = (const float*)d_in[2];
  const float* wq   = (const float*)d_in[3];
  const float* wk   = (const float*)d_in[4];
  const float* wv   = (const float*)d_in[5];
  const float* wo   = (const float*)d_in[6];
  const float* mnw  = (const float*)d_in[7];
  const float* rw   = (const float*)d_in[8];
  const float* w1   = (const float*)d_in[9];
  const float* b1   = (const float*)d_in[10];
  const float* w2   = (const float*)d_in[11];
  const float* b2   = (const float*)d_in[12];
  float* out = (float*)d_out;
  char* ws = (char*)d_ws;

  f16* wqkvT = (f16*)(ws + OFF_WQKVT);
  f16* woT   = (f16*)(ws + OFF_WOT);
  f16* w1T   = (f16*)(ws + OFF_W1T);
  f16* w2T   = (f16*)(ws + OFF_W2T);
  f16* hattn = (f16*)(ws + OFF_HATTN);
  f16* qb    = (f16*)(ws + OFF_Q);
  f16* kb    = (f16*)(ws + OFF_K);
  f16* vtb   = (f16*)(ws + OFF_VT);
  f16* oc    = (f16*)(ws + OFF_OC);
  float* xmid = (float*)(ws + OFF_XMID);
  f16* hmlp  = (f16*)(ws + OFF_HMLP);
  f16* hid   = (f16*)(ws + OFF_HID);
  float* y   = (float*)(ws + OFF_Y);
  float* y2  = (float*)(ws + OFF_Y2);
  int* list  = (int*)(ws + OFF_LIST);
  int2* metaE = (int2*)(ws + OFF_METAE);
  int* metaP  = (int*)(ws + OFF_METAP);
  float2* metaS = (float2*)(ws + OFF_METAS);
  float* bpsum = (float*)(ws + OFF_BPSUM);
  int* cnt   = (int*)(ws + OFF_CNT);
  int* base  = (int*)(ws + OFF_BASE);

  dim3 tb(32, 8, 1);
  transpose_cast_kernel<<<dim3(32, 32, 1), tb, 0, stream>>>(wq, wqkvT, 1024, 1024);
  transpose_cast_kernel<<<dim3(32, 32, 1), tb, 0, stream>>>(wk, wqkvT + 1024 * 1024, 1024, 1024);
  transpose_cast_kernel<<<dim3(32, 32, 1), tb, 0, stream>>>(wv, wqkvT + 2 * 1024 * 1024, 1024, 1024);
  transpose_cast_kernel<<<dim3(32, 32, 1), tb, 0, stream>>>(wo, woT, 1024, 1024);
  transpose_cast_kernel<<<dim3(128, 32, 8), tb, 0, stream>>>(w1, w1T, 1024, 4096);
  transpose_cast_kernel<<<dim3(32, 128, 8), tb, 0, stream>>>(w2, w2T, 4096, 1024);

  rmsnorm_kernel<<<NTOK, 256, 0, stream>>>(x, anw, hattn);
  gemm_qkv_kernel<<<dim3(24, 32), 256, 0, stream>>>(hattn, wqkvT, qb, kb, vtb);
  attn_kernel<<<dim3(32, 32), 256, 0, stream>>>(qb, kb, vtb, am, oc);
  gemm_o_kernel<<<dim3(8, 32), 256, 0, stream>>>(oc, woT, x, xmid);
  rmsnorm_kernel<<<NTOK, 256, 0, stream>>>(xmid, mnw, hmlp);
  router_kernel<<<1024, 256, 0, stream>>>(xmid, mnw, rw, metaE, metaS, bpsum);
  scatter_kernel<<<8, 256, 0, stream>>>(metaE, list, metaP, cnt);
  finalize_kernel<<<1, 256, 0, stream>>>(cnt, bpsum, base, out + (size_t)NTOK * DMODEL);
  gemm_moe1_kernel<<<dim3(32, 32, 8), 256, 0, stream>>>(hmlp, w1T, b1, cnt, base, list, hid);
  gemm_moe2_kernel<<<dim3(8, 32, 16), 256, 0, stream>>>(hid, w2T, b2, cnt, base, y, y2);
  combine_kernel<<<NTOK, 256, 0, stream>>>(xmid, y, y2, metaE, metaP, metaS, base, out);
}

// Round 3
// 907.267 us; speedup vs baseline: 1.0939x; 1.0939x over previous
//
#include <hip/hip_runtime.h>

// ---------------------------------------------------------------------------
// PraxisBlock: rmsnorm -> QKV -> causal MHA -> O+residual -> rmsnorm ->
//              router top2/8 -> gathered expert FFN (gelu) -> combine
// All GEMMs: fp16 MFMA (v_mfma_f32_16x16x32_f16), fp32 accumulate.
// R1: router restructured — no global atomics (was 515us of XCD ping-pong).
// R2: attention re-tiled 64 q-rows/block, 1024 blocks, 32KB LDS.
// R3: XOR-swizzled LDS in gemm128 + split-K x2 for moe2.
// R4/R5 (REVERTED): __syncthreads-based prefetch fails: its vmcnt(0) drain
//     exposes ~600cyc/K-tile regardless of dbuf, and bigger LDS cut the
//     cross-block overlap that was hiding the drain (194us / 201us > 146us).
// R6: gemm256ck — counted-vmcnt pipeline (the m218 lever): 256x256 tile,
//     8 waves, dbuf 128KB LDS, raw s_barrier + inline-asm s_waitcnt vmcnt(8)
//     so tile t+1's loads stay in flight across barriers for one full
//     tile-compute (~600cyc ~= HBM latency). Works at 1 block/CU.
//     Wait arithmetic: at the wait point outstanding = T(t+1):8 + T(t+2):8;
//     vmcnt(8) retires exactly T(t+1). Tail uses vmcnt(0).
//     Applied to moe1 (grid 16,16,8), moe2 (split-K x2, 4,16,16), qkv
//     (dense, 12,16). gemm_o stays on the R3 gemm128. setprio(1) around
//     MFMA clusters (T5: pays only in phase-split schedules).
// ---------------------------------------------------------------------------

typedef _Float16 f16;
typedef _Float16 f16x8 __attribute__((ext_vector_type(8)));
typedef _Float16 f16x4v __attribute__((ext_vector_type(4)));
typedef float f32x4 __attribute__((ext_vector_type(4)));

#define DMODEL 1024
#define NHEAD  16
#define HDIM   64
#define NEXP   8
#define DFFN   4096
#define NBATCH 2
#define NSEQ   2048
#define NTOK   4096   // NBATCH*NSEQ
#define NPAIR  8192   // NTOK*2

// ---- workspace byte offsets (all 256-aligned) ----
#define OFF_WQKVT  0ull                  // 3*1024*1024 f16
#define OFF_WOT    6291456ull            // 1024*1024 f16
#define OFF_W1T    8388608ull            // 8*4096*1024 f16
#define OFF_W2T    75497472ull           // 8*1024*4096 f16
#define OFF_HATTN  142606336ull          // 4096*1024 f16   (dead after gemm_o; y2 reuses)
#define OFF_Q      150994944ull          // 32*2048*64 f16
#define OFF_K      159383552ull
#define OFF_VT     167772160ull
#define OFF_OC     176160768ull          // 4096*1024 f16
#define OFF_XMID   184549376ull          // 4096*1024 f32
#define OFF_HMLP   201326592ull          // 4096*1024 f16
#define OFF_HID    209715200ull          // 8192*4096 f16
#define OFF_Y      276824064ull          // 8192*1024 f32 (split-K half 0, +bias)
#define OFF_Y2     OFF_HATTN             // 8192*1024 f32 (split-K half 1) — hattn/q/k/vt dead by then
#define OFF_LIST   310378496ull          // 8*4096 int
#define OFF_METAE  310509568ull          // 4096 int2
#define OFF_METAP  310542336ull          // 4096 int2
#define OFF_METAS  310575104ull          // 4096 float2
#define OFF_BPSUM  310607872ull          // 1024*8 float (per-block prob sums)
#define OFF_CNT    310640640ull          // 8 int
#define OFF_PSUM   310640704ull          // 8 float
#define OFF_BASE   310640768ull          // 9 int

__device__ __forceinline__ void ldsAsync16(const void* g, void* l) {
  __builtin_amdgcn_global_load_lds((const __attribute__((address_space(1))) void*)g,
                                   (__attribute__((address_space(3))) void*)l, 16, 0, 0);
}

// ---------------- transpose + cast fp32[R][C] -> fp16[C][R] ----------------
__global__ void transpose_cast_kernel(const float* __restrict__ src, f16* __restrict__ dst,
                                      int R, int C) {
  __shared__ float tile[32][33];
  const size_t zoff = (size_t)blockIdx.z * R * C;
  src += zoff; dst += zoff;
  int c0 = blockIdx.x * 32, r0 = blockIdx.y * 32;
  int tx = threadIdx.x, ty = threadIdx.y;
#pragma unroll
  for (int i = 0; i < 4; i++)
    tile[ty + i * 8][tx] = src[(size_t)(r0 + ty + i * 8) * C + c0 + tx];
  __syncthreads();
#pragma unroll
  for (int i = 0; i < 4; i++)
    dst[(size_t)(c0 + ty + i * 8) * R + r0 + tx] = (f16)tile[tx][ty + i * 8];
}

// ---------------- rmsnorm fp32 -> fp16 ----------------
__global__ void rmsnorm_kernel(const float* __restrict__ x, const float* __restrict__ w,
                               f16* __restrict__ out) {
  int t = blockIdx.x, tid = threadIdx.x;
  float4 v = ((const float4*)(x + (size_t)t * DMODEL))[tid];
  float ss = v.x * v.x + v.y * v.y + v.z * v.z + v.w * v.w;
#pragma unroll
  for (int o = 32; o > 0; o >>= 1) ss += __shfl_down(ss, o);
  __shared__ float red[4];
  if ((tid & 63) == 0) red[tid >> 6] = ss;
  __syncthreads();
  float tot = red[0] + red[1] + red[2] + red[3];
  float rstd = rsqrtf(tot / (float)DMODEL + 1e-6f);
  float4 wv = ((const float4*)w)[tid];
  f16x4v o4;
  o4[0] = (f16)(v.x * rstd * wv.x);
  o4[1] = (f16)(v.y * rstd * wv.y);
  o4[2] = (f16)(v.z * rstd * wv.z);
  o4[3] = (f16)(v.w * rstd * wv.w);
  *(f16x4v*)(out + (size_t)t * DMODEL + tid * 4) = o4;
}

// ---------------- shared 128x128xK MFMA core (XOR-swizzled LDS) ----------
// R3 form: stage -> barrier -> compute, two __syncthreads per K-tile. The
// co-resident block (32KB LDS -> ~3 blocks/CU) hides the barrier drain.
// Staging contract: callers must point lane (kc=lane&7, rs=lane>>3) at global
// column chunk (kc ^ rs)*8 of its row, NOT kc*8. LDS[row][c] then holds global
// chunk c^(row&7); fragment reads below un-swizzle with j^(row&7).
template <class EPI>
__device__ __forceinline__ void gemm128(const f16* aP0, const f16* aP1, const f16* aP2, const f16* aP3,
                                        const f16* bP0, const f16* bP1, const f16* bP2, const f16* bP3,
                                        int K, EPI epi) {
  __shared__ __align__(16) f16 sA[128 * 64];
  __shared__ __align__(16) f16 sB[128 * 64];
  const int tid = threadIdx.x;
  const int lane = tid & 63, wave = tid >> 6;
  const int wm = (wave >> 1) * 64, wn = (wave & 1) * 64;
  const int q4 = lane >> 4, l15 = lane & 15;
  const int sw = lane & 7;  // == l15 & 7 == row&7 for fragment rows
  const f16* aP[4] = {aP0, aP1, aP2, aP3};
  const f16* bP[4] = {bP0, bP1, bP2, bP3};
  f32x4 zero = {0.f, 0.f, 0.f, 0.f};
  f32x4 acc[4][4];
#pragma unroll
  for (int i = 0; i < 4; i++)
#pragma unroll
    for (int j = 0; j < 4; j++) acc[i][j] = zero;

  for (int k0 = 0; k0 < K; k0 += 64) {
    __syncthreads();
#pragma unroll
    for (int i = 0; i < 4; i++) {
      ldsAsync16(aP[i] + k0, &sA[(i * 4 + wave) * 512]);
      ldsAsync16(bP[i] + k0, &sB[(i * 4 + wave) * 512]);
    }
    __syncthreads();
#pragma unroll
    for (int kk = 0; kk < 2; kk++) {
      f16x8 af[4], bf[4];
      int jx = ((kk * 4 + q4) ^ sw) * 8;
#pragma unroll
      for (int mi = 0; mi < 4; mi++)
        af[mi] = *(const f16x8*)&sA[(wm + mi * 16 + l15) * 64 + jx];
#pragma unroll
      for (int ni = 0; ni < 4; ni++)
        bf[ni] = *(const f16x8*)&sB[(wn + ni * 16 + l15) * 64 + jx];
#pragma unroll
      for (int mi = 0; mi < 4; mi++)
#pragma unroll
        for (int ni = 0; ni < 4; ni++)
          acc[mi][ni] = __builtin_amdgcn_mfma_f32_16x16x32_f16(af[mi], bf[ni], acc[mi][ni], 0, 0, 0);
    }
  }
#pragma unroll
  for (int mi = 0; mi < 4; mi++)
#pragma unroll
    for (int ni = 0; ni < 4; ni++)
#pragma unroll
      for (int r = 0; r < 4; r++)
        epi(wm + mi * 16 + q4 * 4 + r, wn + ni * 16 + l15, acc[mi][ni][r]);
}

// ---------------- 256x256 counted-vmcnt MFMA core (R6) ----------------
// 512 threads / 8 waves (2M x 4N); per-wave 128x64 output, acc[8][4] f32x4.
// LDS 128KB: dbuf slots of A[256][64] + B[256][64] f16 (XOR-swizzled, same
// contract as gemm128). NT = K/64 (compile-time).
// Pipeline per tile t: compute slot(t&1) -> s_barrier (reads done) ->
// stage T(t+2) into that slot -> s_waitcnt vmcnt(8) (retires T(t+1), leaves
// T(t+2) in flight) -> sched_barrier(0) -> s_barrier. NEVER vmcnt(0) in the
// steady loop; only at the tail.
template <int NT, class EPI>
__device__ __forceinline__ void gemm256ck(const f16* const aP[4], const f16* const bP[4], EPI epi) {
  __shared__ __align__(16) f16 sA[2][256 * 64];
  __shared__ __align__(16) f16 sB[2][256 * 64];
  const int tid = threadIdx.x;
  const int lane = tid & 63, wave = tid >> 6;          // wave 0..7
  const int wm = (wave >> 2) * 128, wn = (wave & 3) * 64;
  const int q4 = lane >> 4, l15 = lane & 15;
  const int sw = l15 & 7;

  auto stage = [&](int t, int slot) {
    const int koff = t * 64;
#pragma unroll
    for (int i = 0; i < 4; i++) {
      ldsAsync16(aP[i] + koff, &sA[slot][(i * 8 + wave) * 512]);
      ldsAsync16(bP[i] + koff, &sB[slot][(i * 8 + wave) * 512]);
    }
  };

  f32x4 zero = {0.f, 0.f, 0.f, 0.f};
  f32x4 acc[8][4];
#pragma unroll
  for (int i = 0; i < 8; i++)
#pragma unroll
    for (int j = 0; j < 4; j++) acc[i][j] = zero;

  // prologue: T0 -> slot0, T1 -> slot1 (16 loads/lane outstanding)
  stage(0, 0);
  stage(1, 1);
  asm volatile("s_waitcnt vmcnt(8)" ::: "memory");   // T0 landed (T1 in flight)
  __builtin_amdgcn_sched_barrier(0);
  __builtin_amdgcn_s_barrier();

  for (int t = 0; t < NT; ++t) {
    const int slot = t & 1;
#pragma unroll
    for (int kk = 0; kk < 2; kk++) {
      f16x8 af[8], bf[4];
      const int jx = ((kk * 4 + q4) ^ sw) * 8;
#pragma unroll
      for (int ni = 0; ni < 4; ni++)
        bf[ni] = *(const f16x8*)&sB[slot][(wn + ni * 16 + l15) * 64 + jx];
#pragma unroll
      for (int mi = 0; mi < 8; mi++)
        af[mi] = *(const f16x8*)&sA[slot][(wm + mi * 16 + l15) * 64 + jx];
      __builtin_amdgcn_s_setprio(1);
#pragma unroll
      for (int mi = 0; mi < 8; mi++)
#pragma unroll
        for (int ni = 0; ni < 4; ni++)
          acc[mi][ni] = __builtin_amdgcn_mfma_f32_16x16x32_f16(af[mi], bf[ni], acc[mi][ni], 0, 0, 0);
      __builtin_amdgcn_s_setprio(0);
    }
    if (t == NT - 1) break;
    __builtin_amdgcn_s_barrier();          // all waves done reading slot
    if (t + 2 < NT) {
      stage(t + 2, slot);                  // outstanding: T(t+1):8 + T(t+2):8
      asm volatile("s_waitcnt vmcnt(8)" ::: "memory");   // T(t+1) landed
    } else {
      asm volatile("s_waitcnt vmcnt(0)" ::: "memory");   // tail: only T(t+1) left
    }
    __builtin_amdgcn_sched_barrier(0);
    __builtin_amdgcn_s_barrier();          // T(t+1) visible to all waves
  }

#pragma unroll
  for (int mi = 0; mi < 8; mi++)
#pragma unroll
    for (int ni = 0; ni < 4; ni++)
#pragma unroll
      for (int r = 0; r < 4; r++)
        epi(wm + mi * 16 + q4 * 4 + r, wn + ni * 16 + l15, acc[mi][ni][r]);
}

// ---------------- QKV projection (N=3072 stacked, 256^2 core) ----------------
__global__ __launch_bounds__(512, 2) void gemm_qkv_kernel(
    const f16* __restrict__ hA, const f16* __restrict__ wT,
    f16* __restrict__ qb, f16* __restrict__ kb, f16* __restrict__ vtb) {
  int mt = blockIdx.y, nt = blockIdx.x;
  int tid = threadIdx.x, lane = tid & 63, wave = tid >> 6;
  int kc = lane & 7, rs8 = lane >> 3;
  int kcs = (kc ^ rs8) * 8;  // swizzled column chunk
  const f16 *a[4], *b[4];
#pragma unroll
  for (int i = 0; i < 4; i++) {
    int row = i * 64 + wave * 8 + rs8;  // 0..255
    a[i] = hA + (size_t)(mt * 256 + row) * DMODEL + kcs;
    b[i] = wT + (size_t)(nt * 256 + row) * DMODEL + kcs;
  }
  int mB = mt * 256, nB = nt * 256;
  gemm256ck<16>(a, b,
    [&](int r, int c, float v) {
      int m = mB + r, n = nB + c;
      int mat = n >> 10, nn = n & 1023;
      int h = nn >> 6, d = nn & 63;
      int bI = m >> 11, s = m & 2047;
      int bh = bI * NHEAD + h;
      f16 hv = (f16)v;
      if (mat == 0)      qb[((size_t)bh * NSEQ + s) * HDIM + d] = hv;
      else if (mat == 1) kb[((size_t)bh * NSEQ + s) * HDIM + d] = hv;
      else               vtb[((size_t)bh * HDIM + d) * NSEQ + s] = hv;
    });
}

// ---------------- O projection + residual (128^2 R3 core) ----------------
__global__ __launch_bounds__(256, 2) void gemm_o_kernel(
    const f16* __restrict__ oc, const f16* __restrict__ woT,
    const float* __restrict__ xin, float* __restrict__ xmid) {
  int mt = blockIdx.y, nt = blockIdx.x;
  int tid = threadIdx.x, lane = tid & 63, wave = tid >> 6;
  int kc = lane & 7, rs = lane >> 3;
  int kcs = (kc ^ rs) * 8;
  const f16 *a[4], *b[4];
#pragma unroll
  for (int i = 0; i < 4; i++) {
    int row = i * 32 + wave * 8 + rs;
    a[i] = oc + (size_t)(mt * 128 + row) * DMODEL + kcs;
    b[i] = woT + (size_t)(nt * 128 + row) * DMODEL + kcs;
  }
  int mB = mt * 128, nB = nt * 128;
  gemm128(a[0], a[1], a[2], a[3], b[0], b[1], b[2], b[3], DMODEL,
    [&](int r, int c, float v) {
      size_t idx = (size_t)(mB + r) * DMODEL + nB + c;
      xmid[idx] = xin[idx] + v;
    });
}

// ---------------- MoE expert GEMM 1: h -> gelu(h*w1+b1) (256^2 core) ------
__global__ __launch_bounds__(512, 2) void gemm_moe1_kernel(
    const f16* __restrict__ hM, const f16* __restrict__ w1T, const float* __restrict__ b1,
    const int* __restrict__ cnt, const int* __restrict__ base, const int* __restrict__ list,
    f16* __restrict__ hid) {
  int e = blockIdx.z, mt = blockIdx.y, nt = blockIdx.x;
  int c_e = cnt[e];
  if (mt * 256 >= c_e) return;
  int tid = threadIdx.x, lane = tid & 63, wave = tid >> 6;
  int kc = lane & 7, rs8 = lane >> 3;
  int kcs = (kc ^ rs8) * 8;
  const f16 *a[4], *b[4];
#pragma unroll
  for (int i = 0; i < 4; i++) {
    int row = i * 64 + wave * 8 + rs8;  // 0..255
    int rr = mt * 256 + row; rr = rr < c_e ? rr : c_e - 1;
    int tok = list[e * NTOK + rr];
    a[i] = hM + (size_t)tok * DMODEL + kcs;
    b[i] = w1T + ((size_t)e * DFFN + nt * 256 + row) * DMODEL + kcs;
  }
  int rowBase = base[e] + mt * 256, nB = nt * 256, mLoc = mt * 256;
  gemm256ck<16>(a, b,
    [&](int r, int c, float v) {
      if (mLoc + r < c_e) {
        float v2 = v + b1[e * DFFN + nB + c];
        float u = 1.5957691216057308f * (v2 + 0.044715f * v2 * v2 * v2); // 2*0.79788456*
        float th = 1.f - 2.f / (__expf(u) + 1.f);                        // tanh
        hid[(size_t)(rowBase + r) * DFFN + nB + c] = (f16)(0.5f * v2 * (1.f + th));
      }
    });
}

// ---------------- MoE expert GEMM 2: hid*w2+b2 -> y (split-K x2, 256^2) ---
__global__ __launch_bounds__(512, 2) void gemm_moe2_kernel(
    const f16* __restrict__ hid, const f16* __restrict__ w2T, const float* __restrict__ b2,
    const int* __restrict__ cnt, const int* __restrict__ base,
    float* __restrict__ y, float* __restrict__ y2) {
  int z = blockIdx.z, e = z >> 1, kh = z & 1;
  int mt = blockIdx.y, nt = blockIdx.x;
  int c_e = cnt[e];
  if (mt * 256 >= c_e) return;
  int tid = threadIdx.x, lane = tid & 63, wave = tid >> 6;
  int kc = lane & 7, rs8 = lane >> 3;
  int kcs = (kc ^ rs8) * 8 + kh * 2048;
  int bse = base[e];
  const f16 *a[4], *b[4];
#pragma unroll
  for (int i = 0; i < 4; i++) {
    int row = i * 64 + wave * 8 + rs8;  // 0..255
    int rr = mt * 256 + row; rr = rr < c_e ? rr : c_e - 1;
    a[i] = hid + (size_t)(bse + rr) * DFFN + kcs;
    b[i] = w2T + ((size_t)e * DMODEL + nt * 256 + row) * DFFN + kcs;
  }
  int nB = nt * 256, mLoc = mt * 256;
  float* yo = kh ? y2 : y;
  gemm256ck<16>(a, b,   // K = 1024 per split-K half
    [&](int r, int c, float v) {
      if (mLoc + r < c_e) {
        float bias = kh ? 0.f : b2[e * DMODEL + nB + c];
        yo[(size_t)(bse + mLoc + r) * DMODEL + nB + c] = v + bias;
      }
    });
}

// ---------------- flash attention (causal + key mask) ----------------
// 64 q-rows per block, 4 waves x 16 q-rows. bh on blockIdx.x so each head's
// K/V stays on one XCD (XCD = linear_id % 8 = bh % 8).
__global__ __launch_bounds__(256, 4) void attn_kernel(
    const f16* __restrict__ qb, const f16* __restrict__ kb, const f16* __restrict__ vtb,
    const int* __restrict__ amask, f16* __restrict__ oc) {
  int bh = blockIdx.x, qt = blockIdx.y;
  int bI = bh >> 4, h = bh & 15;
  int qbase = qt * 64;
  int tid = threadIdx.x, lane = tid & 63, wave = tid >> 6;
  int q4 = lane >> 4, l15 = lane & 15;
  int kc = lane & 7, rs = lane >> 3;

  __shared__ __align__(16) f16 sQ[64 * 64];
  __shared__ __align__(16) f16 sK[64 * 64];
  __shared__ __align__(16) f16 sVT[64 * 64];
  __shared__ __align__(16) f16 sP[4][16 * 64];
  __shared__ int sMask[64];

  const f16* qBH = qb + (size_t)bh * NSEQ * HDIM;
  const f16* kBH = kb + (size_t)bh * NSEQ * HDIM;
  const f16* vBH = vtb + (size_t)bh * HDIM * NSEQ;

#pragma unroll
  for (int i = 0; i < 2; i++) {
    int row = i * 32 + wave * 8 + rs;  // 0..63
    ldsAsync16(qBH + (size_t)(qbase + row) * HDIM + kc * 8, &sQ[(i * 4 + wave) * 512]);
  }

  f32x4 zero = {0.f, 0.f, 0.f, 0.f};
  f32x4 accO[4];
  float mrow[4], lrow[4];
#pragma unroll
  for (int j = 0; j < 4; j++) { accO[j] = zero; mrow[j] = -3.0e38f; lrow[j] = 0.f; }

  f16* sPw = sP[wave];

  for (int kt = 0; kt <= qt; kt++) {
    int kb0 = kt * 64;
    bool diag = (kt == qt);
    __syncthreads();
#pragma unroll
    for (int i = 0; i < 2; i++) {
      int row = i * 32 + wave * 8 + rs;  // 0..63
      ldsAsync16(kBH + (size_t)(kb0 + row) * HDIM + kc * 8, &sK[(i * 4 + wave) * 512]);
      ldsAsync16(vBH + (size_t)row * NSEQ + kb0 + kc * 8, &sVT[(i * 4 + wave) * 512]);
    }
    if (tid < 64) sMask[tid] = amask[bI * NSEQ + kb0 + tid];
    __syncthreads();

    f32x4 accS[4];
#pragma unroll
    for (int j = 0; j < 4; j++) accS[j] = zero;
#pragma unroll
    for (int kk = 0; kk < 2; kk++) {
      f16x8 af = *(const f16x8*)&sQ[(wave * 16 + l15) * 64 + kk * 32 + q4 * 8];
      f16x8 bf[4];
#pragma unroll
      for (int nj = 0; nj < 4; nj++)
        bf[nj] = *(const f16x8*)&sK[(nj * 16 + l15) * 64 + kk * 32 + q4 * 8];
#pragma unroll
      for (int nj = 0; nj < 4; nj++)
        accS[nj] = __builtin_amdgcn_mfma_f32_16x16x32_f16(af, bf[nj], accS[nj], 0, 0, 0);
    }
    bool mok[4];
    int gk[4];
#pragma unroll
    for (int nj = 0; nj < 4; nj++) {
      gk[nj] = nj * 16 + l15;
      mok[nj] = sMask[gk[nj]] > 0;
    }
#pragma unroll
    for (int r = 0; r < 4; r++) {
      int lq = wave * 16 + q4 * 4 + r;  // local q row 0..63; global gq = qbase+lq
      float rm = -3.0e38f;
#pragma unroll
      for (int nj = 0; nj < 4; nj++) {
        float s = accS[nj][r] * 0.125f;
        bool ok = mok[nj] && (!diag || gk[nj] <= lq);
        s = ok ? s : -1.0e9f;
        accS[nj][r] = s;
        rm = fmaxf(rm, s);
      }
#pragma unroll
      for (int o = 1; o < 16; o <<= 1) rm = fmaxf(rm, __shfl_xor(rm, o));
      float mold = mrow[r];
      float mnew = fmaxf(mold, rm);
      float alpha = __expf(mold - mnew);
      float rsum = 0.f;
#pragma unroll
      for (int nj = 0; nj < 4; nj++) {
        float p = __expf(accS[nj][r] - mnew);
        rsum += p;
        sPw[(q4 * 4 + r) * 64 + nj * 16 + l15] = (f16)p;
      }
#pragma unroll
      for (int o = 1; o < 16; o <<= 1) rsum += __shfl_xor(rsum, o);
      lrow[r] = lrow[r] * alpha + rsum;
      mrow[r] = mnew;
#pragma unroll
      for (int dj = 0; dj < 4; dj++) accO[dj][r] *= alpha;
    }
    // PV (sP is per-wave private; compiler's lgkmcnt covers write->read)
#pragma unroll
    for (int kk = 0; kk < 2; kk++) {
      f16x8 pf = *(const f16x8*)&sPw[l15 * 64 + kk * 32 + q4 * 8];
      f16x8 vf[4];
#pragma unroll
      for (int dj = 0; dj < 4; dj++)
        vf[dj] = *(const f16x8*)&sVT[(dj * 16 + l15) * 64 + kk * 32 + q4 * 8];
#pragma unroll
      for (int dj = 0; dj < 4; dj++)
        accO[dj] = __builtin_amdgcn_mfma_f32_16x16x32_f16(pf, vf[dj], accO[dj], 0, 0, 0);
    }
  }
  // epilogue: divide by l, scatter to o_concat[token][h*64+d]
#pragma unroll
  for (int r = 0; r < 4; r++) {
    float inv = 1.f / lrow[r];
    int s = qbase + wave * 16 + q4 * 4 + r;
    size_t rowoff = ((size_t)bI * NSEQ + s) * DMODEL + h * HDIM;
#pragma unroll
    for (int dj = 0; dj < 4; dj++)
      oc[rowoff + dj * 16 + l15] = (f16)(accO[dj][r] * inv);
  }
}

// ---------------- router: wave-per-token, NO global atomics ----------------
__global__ __launch_bounds__(256) void router_kernel(
    const float* __restrict__ xmid, const float* __restrict__ normw,
    const float* __restrict__ rw, int2* __restrict__ metaE,
    float2* __restrict__ metaS, float* __restrict__ blockpsum) {
  int wave = threadIdx.x >> 6, lane = threadIdx.x & 63;
  int t = blockIdx.x * 4 + wave;
  __shared__ float sprob[4][8];

  const float4* xr = (const float4*)(xmid + (size_t)t * DMODEL);
  const float4* wr = (const float4*)normw;
  float4 v[4];
  float ss = 0.f;
#pragma unroll
  for (int i = 0; i < 4; i++) {
    v[i] = xr[lane * 4 + i];
    ss += v[i].x * v[i].x + v[i].y * v[i].y + v[i].z * v[i].z + v[i].w * v[i].w;
  }
#pragma unroll
  for (int o = 32; o > 0; o >>= 1) ss += __shfl_xor(ss, o);
  float rstd = rsqrtf(ss / (float)DMODEL + 1e-6f);

  float part[8] = {0, 0, 0, 0, 0, 0, 0, 0};
#pragma unroll
  for (int i = 0; i < 4; i++) {
    float4 wv = wr[lane * 4 + i];
    float hv[4] = {v[i].x * rstd * wv.x, v[i].y * rstd * wv.y,
                   v[i].z * rstd * wv.z, v[i].w * rstd * wv.w};
#pragma unroll
    for (int j = 0; j < 4; j++) {
      int row = lane * 16 + i * 4 + j;
      const float4* rr = (const float4*)(rw + (size_t)row * NEXP);
      float4 a = rr[0], b = rr[1];
      part[0] += hv[j] * a.x; part[1] += hv[j] * a.y;
      part[2] += hv[j] * a.z; part[3] += hv[j] * a.w;
      part[4] += hv[j] * b.x; part[5] += hv[j] * b.y;
      part[6] += hv[j] * b.z; part[7] += hv[j] * b.w;
    }
  }
#pragma unroll
  for (int o = 1; o < 64; o <<= 1)
#pragma unroll
    for (int e = 0; e < 8; e++) part[e] += __shfl_xor(part[e], o);

  if (lane == 0) {
    float mx = -3.0e38f;
#pragma unroll
    for (int e = 0; e < 8; e++) mx = fmaxf(mx, part[e]);
    float probs[8], sum = 0.f;
#pragma unroll
    for (int e = 0; e < 8; e++) { probs[e] = __expf(part[e] - mx); sum += probs[e]; }
    float inv = 1.f / sum;
#pragma unroll
    for (int e = 0; e < 8; e++) { probs[e] *= inv; sprob[wave][e] = probs[e]; }
    int e0 = 0;
#pragma unroll
    for (int e = 1; e < 8; e++) if (part[e] > part[e0]) e0 = e;
    int e1 = (e0 == 0) ? 1 : 0;
#pragma unroll
    for (int e = 0; e < 8; e++) if (e != e0 && part[e] > part[e1]) e1 = e;
    metaE[t] = make_int2(e0, e1);
    metaS[t] = make_float2(probs[e0], probs[e1]);
  }
  __syncthreads();
  if (threadIdx.x < 8)
    blockpsum[blockIdx.x * 8 + threadIdx.x] =
        sprob[0][threadIdx.x] + sprob[1][threadIdx.x] +
        sprob[2][threadIdx.x] + sprob[3][threadIdx.x];
}

// ---------------- scatter: one block per expert, deterministic prefix sum ----
__global__ __launch_bounds__(256) void scatter_kernel(
    const int2* __restrict__ metaE, int* __restrict__ list,
    int* __restrict__ metaP, int* __restrict__ cnt) {
  int e = blockIdx.x;
  int tid = threadIdx.x, lane = tid & 63, w = tid >> 6;
  __shared__ int wsum[4];
  __shared__ int sbase;
  if (tid == 0) sbase = 0;
  __syncthreads();
  for (int c = 0; c < NTOK; c += 256) {
    int tok = c + tid;
    int2 me = metaE[tok];
    bool m0 = (me.x == e), m1 = (me.y == e);
    bool m = m0 || m1;
    unsigned long long mask = __ballot(m);
    int wpre = __popcll(mask & ((1ull << lane) - 1ull));
    if (lane == 0) wsum[w] = __popcll(mask);
    __syncthreads();
    int base0 = sbase;
    int pre = wpre;
    for (int i = 0; i < w; i++) pre += wsum[i];
    int tot = wsum[0] + wsum[1] + wsum[2] + wsum[3];
    if (m) {
      int pos = base0 + pre;
      list[e * NTOK + base0 + pre] = tok;
      metaP[tok * 2 + (m0 ? 0 : 1)] = pos;
    }
    __syncthreads();
    if (tid == 0) sbase = base0 + tot;
  }
  __syncthreads();
  if (tid == 0) cnt[e] = sbase;
}

// ---------------- finalize: base offsets + balancing loss + counts ----------
__global__ __launch_bounds__(256) void finalize_kernel(
    const int* __restrict__ cnt, const float* __restrict__ blockpsum,
    int* __restrict__ base, float* __restrict__ out_tail) {
  int tid = threadIdx.x;
  int e = tid & 7, slot = tid >> 3;  // 32 slots per expert
  float acc = 0.f;
  for (int i = slot; i < 1024; i += 32) acc += blockpsum[i * 8 + e];
  __shared__ float red[256];
  red[tid] = acc;
  __syncthreads();
  for (int s = 128; s >= 8; s >>= 1) {
    if (tid < s) red[tid] += red[tid + s];
    __syncthreads();
  }
  if (tid == 0) {
    int b = 0;
#pragma unroll
    for (int i = 0; i < 8; i++) { base[i] = b; b += cnt[i]; }
    base[8] = b;
    float loss = 0.f;
#pragma unroll
    for (int i = 0; i < 8; i++)
      loss += ((float)cnt[i] / (float)NPAIR) * (red[i] / (float)NTOK);
    out_tail[0] = loss * (float)NEXP;
#pragma unroll
    for (int i = 0; i < 8; i++) out_tail[1 + i] = (float)cnt[i];
  }
}

// ---------------- final combine (sums split-K halves) ----------------
__global__ void combine_kernel(const float* __restrict__ xmid, const float* __restrict__ yv,
                               const float* __restrict__ yv2,
                               const int2* __restrict__ metaE, const int* __restrict__ metaP,
                               const float2* __restrict__ metaS,
                               const int* __restrict__ base, float* __restrict__ out) {
  int t = blockIdx.x, tid = threadIdx.x;
  int2 me = metaE[t];
  float2 sc = metaS[t];
  size_t s0 = (size_t)(base[me.x] + metaP[t * 2 + 0]) * DMODEL;
  size_t s1 = (size_t)(base[me.y] + metaP[t * 2 + 1]) * DMODEL;
  float4 a = ((const float4*)(xmid + (size_t)t * DMODEL))[tid];
  float4 y0a = ((const float4*)(yv + s0))[tid];
  float4 y0b = ((const float4*)(yv2 + s0))[tid];
  float4 y1a = ((const float4*)(yv + s1))[tid];
  float4 y1b = ((const float4*)(yv2 + s1))[tid];
  float4 o;
  o.x = a.x + sc.x * (y0a.x + y0b.x) + sc.y * (y1a.x + y1b.x);
  o.y = a.y + sc.x * (y0a.y + y0b.y) + sc.y * (y1a.y + y1b.y);
  o.z = a.z + sc.x * (y0a.z + y0b.z) + sc.y * (y1a.z + y1b.z);
  o.w = a.w + sc.x * (y0a.w + y0b.w) + sc.y * (y1a.w + y1b.w);
  ((float4*)(out + (size_t)t * DMODEL))[tid] = o;
}

// ---------------------------------------------------------------------------
extern "C" void kernel_launch(void* const* d_in, const int* in_sizes, int n_in,
                              void* d_out, int out_size, void* d_ws, size_t ws_size,
                              hipStream_t stream) {
  (void)in_sizes; (void)n_in; (void)out_size; (void)ws_size;
  const float* x    = (const float*)d_in[0];
  const int*   am   = (const int*)d_in[1];
  const float* anw  = (const float*)d_in[2];
  const float* wq   = (const float*)d_in[3];
  const float* wk   = (const float*)d_in[4];
  const float* wv   = (const float*)d_in[5];
  const float* wo   = (const float*)d_in[6];
  const float* mnw  = (const float*)d_in[7];
  const float* rw   = (const float*)d_in[8];
  const float* w1   = (const float*)d_in[9];
  const float* b1   = (const float*)d_in[10];
  const float* w2   = (const float*)d_in[11];
  const float* b2   = (const float*)d_in[12];
  float* out = (float*)d_out;
  char* ws = (char*)d_ws;

  f16* wqkvT = (f16*)(ws + OFF_WQKVT);
  f16* woT   = (f16*)(ws + OFF_WOT);
  f16* w1T   = (f16*)(ws + OFF_W1T);
  f16* w2T   = (f16*)(ws + OFF_W2T);
  f16* hattn = (f16*)(ws + OFF_HATTN);
  f16* qb    = (f16*)(ws + OFF_Q);
  f16* kb    = (f16*)(ws + OFF_K);
  f16* vtb   = (f16*)(ws + OFF_VT);
  f16* oc    = (f16*)(ws + OFF_OC);
  float* xmid = (float*)(ws + OFF_XMID);
  f16* hmlp  = (f16*)(ws + OFF_HMLP);
  f16* hid   = (f16*)(ws + OFF_HID);
  float* y   = (float*)(ws + OFF_Y);
  float* y2  = (float*)(ws + OFF_Y2);
  int* list  = (int*)(ws + OFF_LIST);
  int2* metaE = (int2*)(ws + OFF_METAE);
  int* metaP  = (int*)(ws + OFF_METAP);
  float2* metaS = (float2*)(ws + OFF_METAS);
  float* bpsum = (float*)(ws + OFF_BPSUM);
  int* cnt   = (int*)(ws + OFF_CNT);
  int* base  = (int*)(ws + OFF_BASE);

  dim3 tb(32, 8, 1);
  transpose_cast_kernel<<<dim3(32, 32, 1), tb, 0, stream>>>(wq, wqkvT, 1024, 1024);
  transpose_cast_kernel<<<dim3(32, 32, 1), tb, 0, stream>>>(wk, wqkvT + 1024 * 1024, 1024, 1024);
  transpose_cast_kernel<<<dim3(32, 32, 1), tb, 0, stream>>>(wv, wqkvT + 2 * 1024 * 1024, 1024, 1024);
  transpose_cast_kernel<<<dim3(32, 32, 1), tb, 0, stream>>>(wo, woT, 1024, 1024);
  transpose_cast_kernel<<<dim3(128, 32, 8), tb, 0, stream>>>(w1, w1T, 1024, 4096);
  transpose_cast_kernel<<<dim3(32, 128, 8), tb, 0, stream>>>(w2, w2T, 4096, 1024);

  rmsnorm_kernel<<<NTOK, 256, 0, stream>>>(x, anw, hattn);
  gemm_qkv_kernel<<<dim3(12, 16), 512, 0, stream>>>(hattn, wqkvT, qb, kb, vtb);
  attn_kernel<<<dim3(32, 32), 256, 0, stream>>>(qb, kb, vtb, am, oc);
  gemm_o_kernel<<<dim3(8, 32), 256, 0, stream>>>(oc, woT, x, xmid);
  rmsnorm_kernel<<<NTOK, 256, 0, stream>>>(xmid, mnw, hmlp);
  router_kernel<<<1024, 256, 0, stream>>>(xmid, mnw, rw, metaE, metaS, bpsum);
  scatter_kernel<<<8, 256, 0, stream>>>(metaE, list, metaP, cnt);
  finalize_kernel<<<1, 256, 0, stream>>>(cnt, bpsum, base, out + (size_t)NTOK * DMODEL);
  gemm_moe1_kernel<<<dim3(16, 16, 8), 512, 0, stream>>>(hmlp, w1T, b1, cnt, base, list, hid);
  gemm_moe2_kernel<<<dim3(4, 16, 16), 512, 0, stream>>>(hid, w2T, b2, cnt, base, y, y2);
  combine_kernel<<<NTOK, 256, 0, stream>>>(xmid, y, y2, metaE, metaP, metaS, base, out);
}

// Round 4
// 829.960 us; speedup vs baseline: 1.1957x; 1.0931x over previous
//
#include <hip/hip_runtime.h>

// ---------------------------------------------------------------------------
// PraxisBlock: rmsnorm -> QKV -> causal MHA -> O+residual -> rmsnorm ->
//              router top2/8 -> gathered expert FFN (gelu) -> combine
// All GEMMs: fp16 MFMA (v_mfma_f32_16x16x32_f16), fp32 accumulate.
// R1: router restructured — no global atomics (was 515us of XCD ping-pong).
// R2: attention re-tiled 64 q-rows/block, 1024 blocks, 32KB LDS.
// R3: XOR-swizzled LDS in gemm128 + split-K x2 for moe2.  [BEST: 851us]
// R4/R5/R6 (ALL REVERTED): 256^2 tile / dbuf / counted-vmcnt pipelines all
//     land 194-201us on moe1 vs R3's 146us. R6 (counted vmcnt, 1 blk/CU) was
//     bit-identical to R4 (plain syncthreads) -> schedule is not the binding
//     constraint at 256^2; the 128^2 core with ~3 co-resident blocks/CU is
//     the measured optimum for these K=1024 gathered GEMMs.
// R7: full revert to R3 GEMM config + vectorized transpose_cast (G13):
//     64x64 tiles, float4 16B/lane reads, f16x4 8B/lane writes (was 4B/2B
//     scalar). 432MB of transpose traffic -> expect ~2x on those dispatches.
// ---------------------------------------------------------------------------

typedef _Float16 f16;
typedef _Float16 f16x8 __attribute__((ext_vector_type(8)));
typedef _Float16 f16x4v __attribute__((ext_vector_type(4)));
typedef float f32x4 __attribute__((ext_vector_type(4)));

#define DMODEL 1024
#define NHEAD  16
#define HDIM   64
#define NEXP   8
#define DFFN   4096
#define NBATCH 2
#define NSEQ   2048
#define NTOK   4096   // NBATCH*NSEQ
#define NPAIR  8192   // NTOK*2

// ---- workspace byte offsets (all 256-aligned) ----
#define OFF_WQKVT  0ull                  // 3*1024*1024 f16
#define OFF_WOT    6291456ull            // 1024*1024 f16
#define OFF_W1T    8388608ull            // 8*4096*1024 f16
#define OFF_W2T    75497472ull           // 8*1024*4096 f16
#define OFF_HATTN  142606336ull          // 4096*1024 f16   (dead after gemm_o; y2 reuses)
#define OFF_Q      150994944ull          // 32*2048*64 f16
#define OFF_K      159383552ull
#define OFF_VT     167772160ull
#define OFF_OC     176160768ull          // 4096*1024 f16
#define OFF_XMID   184549376ull          // 4096*1024 f32
#define OFF_HMLP   201326592ull          // 4096*1024 f16
#define OFF_HID    209715200ull          // 8192*4096 f16
#define OFF_Y      276824064ull          // 8192*1024 f32 (split-K half 0, +bias)
#define OFF_Y2     OFF_HATTN             // 8192*1024 f32 (split-K half 1) — hattn/q/k/vt dead by then
#define OFF_LIST   310378496ull          // 8*4096 int
#define OFF_METAE  310509568ull          // 4096 int2
#define OFF_METAP  310542336ull          // 4096 int2
#define OFF_METAS  310575104ull          // 4096 float2
#define OFF_BPSUM  310607872ull          // 1024*8 float (per-block prob sums)
#define OFF_CNT    310640640ull          // 8 int
#define OFF_PSUM   310640704ull          // 8 float
#define OFF_BASE   310640768ull          // 9 int

__device__ __forceinline__ void ldsAsync16(const void* g, void* l) {
  __builtin_amdgcn_global_load_lds((const __attribute__((address_space(1))) void*)g,
                                   (__attribute__((address_space(3))) void*)l, 16, 0, 0);
}

// ---------------- transpose + cast fp32[R][C] -> fp16[C][R] ----------------
// R7: 64x64 tile, 256 threads. Reads float4 (16B/lane, 256B/wave-row),
// writes f16x4 (8B/lane, 128B contiguous per 16-lane group). LDS [64][65]:
// both the row-major write-in and column read-out are <=2-way bank aliased
// (free). R and C are multiples of 64.
__global__ __launch_bounds__(256) void transpose_cast_kernel(
    const float* __restrict__ src, f16* __restrict__ dst, int R, int C) {
  __shared__ float tile[64][65];
  const size_t zoff = (size_t)blockIdx.z * R * C;
  src += zoff; dst += zoff;
  int c0 = blockIdx.x * 64, r0 = blockIdx.y * 64;
  int tid = threadIdx.x;
  int c4 = tid & 15, rr = tid >> 4;   // read: 16 float4-cols x 16 rows
#pragma unroll
  for (int i = 0; i < 4; i++) {
    int row = rr + i * 16;
    float4 v = *(const float4*)&src[(size_t)(r0 + row) * C + c0 + c4 * 4];
    tile[row][c4 * 4 + 0] = v.x;
    tile[row][c4 * 4 + 1] = v.y;
    tile[row][c4 * 4 + 2] = v.z;
    tile[row][c4 * 4 + 3] = v.w;
  }
  __syncthreads();
  int r4 = tid & 15, cc = tid >> 4;   // write: 16 f16x4 r-chunks x 16 cols
#pragma unroll
  for (int i = 0; i < 4; i++) {
    int col = cc + i * 16;
    f16x4v o;
    o[0] = (f16)tile[r4 * 4 + 0][col];
    o[1] = (f16)tile[r4 * 4 + 1][col];
    o[2] = (f16)tile[r4 * 4 + 2][col];
    o[3] = (f16)tile[r4 * 4 + 3][col];
    *(f16x4v*)&dst[(size_t)(c0 + col) * R + r0 + r4 * 4] = o;
  }
}

// ---------------- rmsnorm fp32 -> fp16 ----------------
__global__ void rmsnorm_kernel(const float* __restrict__ x, const float* __restrict__ w,
                               f16* __restrict__ out) {
  int t = blockIdx.x, tid = threadIdx.x;
  float4 v = ((const float4*)(x + (size_t)t * DMODEL))[tid];
  float ss = v.x * v.x + v.y * v.y + v.z * v.z + v.w * v.w;
#pragma unroll
  for (int o = 32; o > 0; o >>= 1) ss += __shfl_down(ss, o);
  __shared__ float red[4];
  if ((tid & 63) == 0) red[tid >> 6] = ss;
  __syncthreads();
  float tot = red[0] + red[1] + red[2] + red[3];
  float rstd = rsqrtf(tot / (float)DMODEL + 1e-6f);
  float4 wv = ((const float4*)w)[tid];
  f16x4v o4;
  o4[0] = (f16)(v.x * rstd * wv.x);
  o4[1] = (f16)(v.y * rstd * wv.y);
  o4[2] = (f16)(v.z * rstd * wv.z);
  o4[3] = (f16)(v.w * rstd * wv.w);
  *(f16x4v*)(out + (size_t)t * DMODEL + tid * 4) = o4;
}

// ---------------- shared 128x128xK MFMA core (XOR-swizzled LDS) ----------
// R3 form: stage -> barrier -> compute, two __syncthreads per K-tile. The
// co-resident blocks (32KB LDS -> ~3 blocks/CU) hide the barrier drain.
// Staging contract: callers must point lane (kc=lane&7, rs=lane>>3) at global
// column chunk (kc ^ rs)*8 of its row, NOT kc*8. LDS[row][c] then holds global
// chunk c^(row&7); fragment reads below un-swizzle with j^(row&7).
template <class EPI>
__device__ __forceinline__ void gemm128(const f16* aP0, const f16* aP1, const f16* aP2, const f16* aP3,
                                        const f16* bP0, const f16* bP1, const f16* bP2, const f16* bP3,
                                        int K, EPI epi) {
  __shared__ __align__(16) f16 sA[128 * 64];
  __shared__ __align__(16) f16 sB[128 * 64];
  const int tid = threadIdx.x;
  const int lane = tid & 63, wave = tid >> 6;
  const int wm = (wave >> 1) * 64, wn = (wave & 1) * 64;
  const int q4 = lane >> 4, l15 = lane & 15;
  const int sw = lane & 7;  // == l15 & 7 == row&7 for fragment rows
  const f16* aP[4] = {aP0, aP1, aP2, aP3};
  const f16* bP[4] = {bP0, bP1, bP2, bP3};
  f32x4 zero = {0.f, 0.f, 0.f, 0.f};
  f32x4 acc[4][4];
#pragma unroll
  for (int i = 0; i < 4; i++)
#pragma unroll
    for (int j = 0; j < 4; j++) acc[i][j] = zero;

  for (int k0 = 0; k0 < K; k0 += 64) {
    __syncthreads();
#pragma unroll
    for (int i = 0; i < 4; i++) {
      ldsAsync16(aP[i] + k0, &sA[(i * 4 + wave) * 512]);
      ldsAsync16(bP[i] + k0, &sB[(i * 4 + wave) * 512]);
    }
    __syncthreads();
#pragma unroll
    for (int kk = 0; kk < 2; kk++) {
      f16x8 af[4], bf[4];
      int jx = ((kk * 4 + q4) ^ sw) * 8;
#pragma unroll
      for (int mi = 0; mi < 4; mi++)
        af[mi] = *(const f16x8*)&sA[(wm + mi * 16 + l15) * 64 + jx];
#pragma unroll
      for (int ni = 0; ni < 4; ni++)
        bf[ni] = *(const f16x8*)&sB[(wn + ni * 16 + l15) * 64 + jx];
#pragma unroll
      for (int mi = 0; mi < 4; mi++)
#pragma unroll
        for (int ni = 0; ni < 4; ni++)
          acc[mi][ni] = __builtin_amdgcn_mfma_f32_16x16x32_f16(af[mi], bf[ni], acc[mi][ni], 0, 0, 0);
    }
  }
#pragma unroll
  for (int mi = 0; mi < 4; mi++)
#pragma unroll
    for (int ni = 0; ni < 4; ni++)
#pragma unroll
      for (int r = 0; r < 4; r++)
        epi(wm + mi * 16 + q4 * 4 + r, wn + ni * 16 + l15, acc[mi][ni][r]);
}

// ---------------- QKV projection (N=3072 stacked) ----------------
__global__ __launch_bounds__(256, 2) void gemm_qkv_kernel(
    const f16* __restrict__ hA, const f16* __restrict__ wT,
    f16* __restrict__ qb, f16* __restrict__ kb, f16* __restrict__ vtb) {
  int mt = blockIdx.y, nt = blockIdx.x;
  int tid = threadIdx.x, lane = tid & 63, wave = tid >> 6;
  int kc = lane & 7, rs = lane >> 3;
  int kcs = (kc ^ rs) * 8;  // swizzled column chunk
  const f16 *a[4], *b[4];
#pragma unroll
  for (int i = 0; i < 4; i++) {
    int row = i * 32 + wave * 8 + rs;
    a[i] = hA + (size_t)(mt * 128 + row) * DMODEL + kcs;
    b[i] = wT + (size_t)(nt * 128 + row) * DMODEL + kcs;
  }
  int mB = mt * 128, nB = nt * 128;
  gemm128(a[0], a[1], a[2], a[3], b[0], b[1], b[2], b[3], DMODEL,
    [&](int r, int c, float v) {
      int m = mB + r, n = nB + c;
      int mat = n >> 10, nn = n & 1023;
      int h = nn >> 6, d = nn & 63;
      int bI = m >> 11, s = m & 2047;
      int bh = bI * NHEAD + h;
      f16 hv = (f16)v;
      if (mat == 0)      qb[((size_t)bh * NSEQ + s) * HDIM + d] = hv;
      else if (mat == 1) kb[((size_t)bh * NSEQ + s) * HDIM + d] = hv;
      else               vtb[((size_t)bh * HDIM + d) * NSEQ + s] = hv;
    });
}

// ---------------- O projection + residual ----------------
__global__ __launch_bounds__(256, 2) void gemm_o_kernel(
    const f16* __restrict__ oc, const f16* __restrict__ woT,
    const float* __restrict__ xin, float* __restrict__ xmid) {
  int mt = blockIdx.y, nt = blockIdx.x;
  int tid = threadIdx.x, lane = tid & 63, wave = tid >> 6;
  int kc = lane & 7, rs = lane >> 3;
  int kcs = (kc ^ rs) * 8;
  const f16 *a[4], *b[4];
#pragma unroll
  for (int i = 0; i < 4; i++) {
    int row = i * 32 + wave * 8 + rs;
    a[i] = oc + (size_t)(mt * 128 + row) * DMODEL + kcs;
    b[i] = woT + (size_t)(nt * 128 + row) * DMODEL + kcs;
  }
  int mB = mt * 128, nB = nt * 128;
  gemm128(a[0], a[1], a[2], a[3], b[0], b[1], b[2], b[3], DMODEL,
    [&](int r, int c, float v) {
      size_t idx = (size_t)(mB + r) * DMODEL + nB + c;
      xmid[idx] = xin[idx] + v;
    });
}

// ---------------- MoE expert GEMM 1: h -> gelu(h*w1+b1) ----------------
__global__ __launch_bounds__(256, 2) void gemm_moe1_kernel(
    const f16* __restrict__ hM, const f16* __restrict__ w1T, const float* __restrict__ b1,
    const int* __restrict__ cnt, const int* __restrict__ base, const int* __restrict__ list,
    f16* __restrict__ hid) {
  int e = blockIdx.z, mt = blockIdx.y, nt = blockIdx.x;
  int c_e = cnt[e];
  if (mt * 128 >= c_e) return;
  int tid = threadIdx.x, lane = tid & 63, wave = tid >> 6;
  int kc = lane & 7, rs = lane >> 3;
  int kcs = (kc ^ rs) * 8;
  const f16 *a[4], *b[4];
#pragma unroll
  for (int i = 0; i < 4; i++) {
    int row = i * 32 + wave * 8 + rs;
    int rr = mt * 128 + row; rr = rr < c_e ? rr : c_e - 1;
    int tok = list[e * NTOK + rr];
    a[i] = hM + (size_t)tok * DMODEL + kcs;
    b[i] = w1T + ((size_t)e * DFFN + nt * 128 + row) * DMODEL + kcs;
  }
  int rowBase = base[e] + mt * 128, nB = nt * 128, mLoc = mt * 128;
  gemm128(a[0], a[1], a[2], a[3], b[0], b[1], b[2], b[3], DMODEL,
    [&](int r, int c, float v) {
      if (mLoc + r < c_e) {
        float v2 = v + b1[e * DFFN + nB + c];
        float u = 1.5957691216057308f * (v2 + 0.044715f * v2 * v2 * v2); // 2*0.79788456*
        float th = 1.f - 2.f / (__expf(u) + 1.f);                        // tanh
        hid[(size_t)(rowBase + r) * DFFN + nB + c] = (f16)(0.5f * v2 * (1.f + th));
      }
    });
}

// ---------------- MoE expert GEMM 2: hid*w2+b2 -> y (split-K x2) ----------
__global__ __launch_bounds__(256, 2) void gemm_moe2_kernel(
    const f16* __restrict__ hid, const f16* __restrict__ w2T, const float* __restrict__ b2,
    const int* __restrict__ cnt, const int* __restrict__ base,
    float* __restrict__ y, float* __restrict__ y2) {
  int z = blockIdx.z, e = z >> 1, kh = z & 1;
  int mt = blockIdx.y, nt = blockIdx.x;
  int c_e = cnt[e];
  if (mt * 128 >= c_e) return;
  int tid = threadIdx.x, lane = tid & 63, wave = tid >> 6;
  int kc = lane & 7, rs = lane >> 3;
  int kcs = (kc ^ rs) * 8 + kh * 2048;
  int bse = base[e];
  const f16 *a[4], *b[4];
#pragma unroll
  for (int i = 0; i < 4; i++) {
    int row = i * 32 + wave * 8 + rs;
    int rr = mt * 128 + row; rr = rr < c_e ? rr : c_e - 1;
    a[i] = hid + (size_t)(bse + rr) * DFFN + kcs;
    b[i] = w2T + ((size_t)e * DMODEL + nt * 128 + row) * DFFN + kcs;
  }
  int nB = nt * 128, mLoc = mt * 128;
  float* yo = kh ? y2 : y;
  gemm128(a[0], a[1], a[2], a[3], b[0], b[1], b[2], b[3], 2048,
    [&](int r, int c, float v) {
      if (mLoc + r < c_e) {
        float bias = kh ? 0.f : b2[e * DMODEL + nB + c];
        yo[(size_t)(bse + mLoc + r) * DMODEL + nB + c] = v + bias;
      }
    });
}

// ---------------- flash attention (causal + key mask) ----------------
// 64 q-rows per block, 4 waves x 16 q-rows. bh on blockIdx.x so each head's
// K/V stays on one XCD (XCD = linear_id % 8 = bh % 8).
__global__ __launch_bounds__(256, 4) void attn_kernel(
    const f16* __restrict__ qb, const f16* __restrict__ kb, const f16* __restrict__ vtb,
    const int* __restrict__ amask, f16* __restrict__ oc) {
  int bh = blockIdx.x, qt = blockIdx.y;
  int bI = bh >> 4, h = bh & 15;
  int qbase = qt * 64;
  int tid = threadIdx.x, lane = tid & 63, wave = tid >> 6;
  int q4 = lane >> 4, l15 = lane & 15;
  int kc = lane & 7, rs = lane >> 3;

  __shared__ __align__(16) f16 sQ[64 * 64];
  __shared__ __align__(16) f16 sK[64 * 64];
  __shared__ __align__(16) f16 sVT[64 * 64];
  __shared__ __align__(16) f16 sP[4][16 * 64];
  __shared__ int sMask[64];

  const f16* qBH = qb + (size_t)bh * NSEQ * HDIM;
  const f16* kBH = kb + (size_t)bh * NSEQ * HDIM;
  const f16* vBH = vtb + (size_t)bh * HDIM * NSEQ;

#pragma unroll
  for (int i = 0; i < 2; i++) {
    int row = i * 32 + wave * 8 + rs;  // 0..63
    ldsAsync16(qBH + (size_t)(qbase + row) * HDIM + kc * 8, &sQ[(i * 4 + wave) * 512]);
  }

  f32x4 zero = {0.f, 0.f, 0.f, 0.f};
  f32x4 accO[4];
  float mrow[4], lrow[4];
#pragma unroll
  for (int j = 0; j < 4; j++) { accO[j] = zero; mrow[j] = -3.0e38f; lrow[j] = 0.f; }

  f16* sPw = sP[wave];

  for (int kt = 0; kt <= qt; kt++) {
    int kb0 = kt * 64;
    bool diag = (kt == qt);
    __syncthreads();
#pragma unroll
    for (int i = 0; i < 2; i++) {
      int row = i * 32 + wave * 8 + rs;  // 0..63
      ldsAsync16(kBH + (size_t)(kb0 + row) * HDIM + kc * 8, &sK[(i * 4 + wave) * 512]);
      ldsAsync16(vBH + (size_t)row * NSEQ + kb0 + kc * 8, &sVT[(i * 4 + wave) * 512]);
    }
    if (tid < 64) sMask[tid] = amask[bI * NSEQ + kb0 + tid];
    __syncthreads();

    f32x4 accS[4];
#pragma unroll
    for (int j = 0; j < 4; j++) accS[j] = zero;
#pragma unroll
    for (int kk = 0; kk < 2; kk++) {
      f16x8 af = *(const f16x8*)&sQ[(wave * 16 + l15) * 64 + kk * 32 + q4 * 8];
      f16x8 bf[4];
#pragma unroll
      for (int nj = 0; nj < 4; nj++)
        bf[nj] = *(const f16x8*)&sK[(nj * 16 + l15) * 64 + kk * 32 + q4 * 8];
#pragma unroll
      for (int nj = 0; nj < 4; nj++)
        accS[nj] = __builtin_amdgcn_mfma_f32_16x16x32_f16(af, bf[nj], accS[nj], 0, 0, 0);
    }
    bool mok[4];
    int gk[4];
#pragma unroll
    for (int nj = 0; nj < 4; nj++) {
      gk[nj] = nj * 16 + l15;
      mok[nj] = sMask[gk[nj]] > 0;
    }
#pragma unroll
    for (int r = 0; r < 4; r++) {
      int lq = wave * 16 + q4 * 4 + r;  // local q row 0..63; global gq = qbase+lq
      float rm = -3.0e38f;
#pragma unroll
      for (int nj = 0; nj < 4; nj++) {
        float s = accS[nj][r] * 0.125f;
        bool ok = mok[nj] && (!diag || gk[nj] <= lq);
        s = ok ? s : -1.0e9f;
        accS[nj][r] = s;
        rm = fmaxf(rm, s);
      }
#pragma unroll
      for (int o = 1; o < 16; o <<= 1) rm = fmaxf(rm, __shfl_xor(rm, o));
      float mold = mrow[r];
      float mnew = fmaxf(mold, rm);
      float alpha = __expf(mold - mnew);
      float rsum = 0.f;
#pragma unroll
      for (int nj = 0; nj < 4; nj++) {
        float p = __expf(accS[nj][r] - mnew);
        rsum += p;
        sPw[(q4 * 4 + r) * 64 + nj * 16 + l15] = (f16)p;
      }
#pragma unroll
      for (int o = 1; o < 16; o <<= 1) rsum += __shfl_xor(rsum, o);
      lrow[r] = lrow[r] * alpha + rsum;
      mrow[r] = mnew;
#pragma unroll
      for (int dj = 0; dj < 4; dj++) accO[dj][r] *= alpha;
    }
    // PV (sP is per-wave private; compiler's lgkmcnt covers write->read)
#pragma unroll
    for (int kk = 0; kk < 2; kk++) {
      f16x8 pf = *(const f16x8*)&sPw[l15 * 64 + kk * 32 + q4 * 8];
      f16x8 vf[4];
#pragma unroll
      for (int dj = 0; dj < 4; dj++)
        vf[dj] = *(const f16x8*)&sVT[(dj * 16 + l15) * 64 + kk * 32 + q4 * 8];
#pragma unroll
      for (int dj = 0; dj < 4; dj++)
        accO[dj] = __builtin_amdgcn_mfma_f32_16x16x32_f16(pf, vf[dj], accO[dj], 0, 0, 0);
    }
  }
  // epilogue: divide by l, scatter to o_concat[token][h*64+d]
#pragma unroll
  for (int r = 0; r < 4; r++) {
    float inv = 1.f / lrow[r];
    int s = qbase + wave * 16 + q4 * 4 + r;
    size_t rowoff = ((size_t)bI * NSEQ + s) * DMODEL + h * HDIM;
#pragma unroll
    for (int dj = 0; dj < 4; dj++)
      oc[rowoff + dj * 16 + l15] = (f16)(accO[dj][r] * inv);
  }
}

// ---------------- router: wave-per-token, NO global atomics ----------------
__global__ __launch_bounds__(256) void router_kernel(
    const float* __restrict__ xmid, const float* __restrict__ normw,
    const float* __restrict__ rw, int2* __restrict__ metaE,
    float2* __restrict__ metaS, float* __restrict__ blockpsum) {
  int wave = threadIdx.x >> 6, lane = threadIdx.x & 63;
  int t = blockIdx.x * 4 + wave;
  __shared__ float sprob[4][8];

  const float4* xr = (const float4*)(xmid + (size_t)t * DMODEL);
  const float4* wr = (const float4*)normw;
  float4 v[4];
  float ss = 0.f;
#pragma unroll
  for (int i = 0; i < 4; i++) {
    v[i] = xr[lane * 4 + i];
    ss += v[i].x * v[i].x + v[i].y * v[i].y + v[i].z * v[i].z + v[i].w * v[i].w;
  }
#pragma unroll
  for (int o = 32; o > 0; o >>= 1) ss += __shfl_xor(ss, o);
  float rstd = rsqrtf(ss / (float)DMODEL + 1e-6f);

  float part[8] = {0, 0, 0, 0, 0, 0, 0, 0};
#pragma unroll
  for (int i = 0; i < 4; i++) {
    float4 wv = wr[lane * 4 + i];
    float hv[4] = {v[i].x * rstd * wv.x, v[i].y * rstd * wv.y,
                   v[i].z * rstd * wv.z, v[i].w * rstd * wv.w};
#pragma unroll
    for (int j = 0; j < 4; j++) {
      int row = lane * 16 + i * 4 + j;
      const float4* rr = (const float4*)(rw + (size_t)row * NEXP);
      float4 a = rr[0], b = rr[1];
      part[0] += hv[j] * a.x; part[1] += hv[j] * a.y;
      part[2] += hv[j] * a.z; part[3] += hv[j] * a.w;
      part[4] += hv[j] * b.x; part[5] += hv[j] * b.y;
      part[6] += hv[j] * b.z; part[7] += hv[j] * b.w;
    }
  }
#pragma unroll
  for (int o = 1; o < 64; o <<= 1)
#pragma unroll
    for (int e = 0; e < 8; e++) part[e] += __shfl_xor(part[e], o);

  if (lane == 0) {
    float mx = -3.0e38f;
#pragma unroll
    for (int e = 0; e < 8; e++) mx = fmaxf(mx, part[e]);
    float probs[8], sum = 0.f;
#pragma unroll
    for (int e = 0; e < 8; e++) { probs[e] = __expf(part[e] - mx); sum += probs[e]; }
    float inv = 1.f / sum;
#pragma unroll
    for (int e = 0; e < 8; e++) { probs[e] *= inv; sprob[wave][e] = probs[e]; }
    int e0 = 0;
#pragma unroll
    for (int e = 1; e < 8; e++) if (part[e] > part[e0]) e0 = e;
    int e1 = (e0 == 0) ? 1 : 0;
#pragma unroll
    for (int e = 0; e < 8; e++) if (e != e0 && part[e] > part[e1]) e1 = e;
    metaE[t] = make_int2(e0, e1);
    metaS[t] = make_float2(probs[e0], probs[e1]);
  }
  __syncthreads();
  if (threadIdx.x < 8)
    blockpsum[blockIdx.x * 8 + threadIdx.x] =
        sprob[0][threadIdx.x] + sprob[1][threadIdx.x] +
        sprob[2][threadIdx.x] + sprob[3][threadIdx.x];
}

// ---------------- scatter: one block per expert, deterministic prefix sum ----
__global__ __launch_bounds__(256) void scatter_kernel(
    const int2* __restrict__ metaE, int* __restrict__ list,
    int* __restrict__ metaP, int* __restrict__ cnt) {
  int e = blockIdx.x;
  int tid = threadIdx.x, lane = tid & 63, w = tid >> 6;
  __shared__ int wsum[4];
  __shared__ int sbase;
  if (tid == 0) sbase = 0;
  __syncthreads();
  for (int c = 0; c < NTOK; c += 256) {
    int tok = c + tid;
    int2 me = metaE[tok];
    bool m0 = (me.x == e), m1 = (me.y == e);
    bool m = m0 || m1;
    unsigned long long mask = __ballot(m);
    int wpre = __popcll(mask & ((1ull << lane) - 1ull));
    if (lane == 0) wsum[w] = __popcll(mask);
    __syncthreads();
    int base0 = sbase;
    int pre = wpre;
    for (int i = 0; i < w; i++) pre += wsum[i];
    int tot = wsum[0] + wsum[1] + wsum[2] + wsum[3];
    if (m) {
      int pos = base0 + pre;
      list[e * NTOK + base0 + pre] = tok;
      metaP[tok * 2 + (m0 ? 0 : 1)] = pos;
    }
    __syncthreads();
    if (tid == 0) sbase = base0 + tot;
  }
  __syncthreads();
  if (tid == 0) cnt[e] = sbase;
}

// ---------------- finalize: base offsets + balancing loss + counts ----------
__global__ __launch_bounds__(256) void finalize_kernel(
    const int* __restrict__ cnt, const float* __restrict__ blockpsum,
    int* __restrict__ base, float* __restrict__ out_tail) {
  int tid = threadIdx.x;
  int e = tid & 7, slot = tid >> 3;  // 32 slots per expert
  float acc = 0.f;
  for (int i = slot; i < 1024; i += 32) acc += blockpsum[i * 8 + e];
  __shared__ float red[256];
  red[tid] = acc;
  __syncthreads();
  for (int s = 128; s >= 8; s >>= 1) {
    if (tid < s) red[tid] += red[tid + s];
    __syncthreads();
  }
  if (tid == 0) {
    int b = 0;
#pragma unroll
    for (int i = 0; i < 8; i++) { base[i] = b; b += cnt[i]; }
    base[8] = b;
    float loss = 0.f;
#pragma unroll
    for (int i = 0; i < 8; i++)
      loss += ((float)cnt[i] / (float)NPAIR) * (red[i] / (float)NTOK);
    out_tail[0] = loss * (float)NEXP;
#pragma unroll
    for (int i = 0; i < 8; i++) out_tail[1 + i] = (float)cnt[i];
  }
}

// ---------------- final combine (sums split-K halves) ----------------
__global__ void combine_kernel(const float* __restrict__ xmid, const float* __restrict__ yv,
                               const float* __restrict__ yv2,
                               const int2* __restrict__ metaE, const int* __restrict__ metaP,
                               const float2* __restrict__ metaS,
                               const int* __restrict__ base, float* __restrict__ out) {
  int t = blockIdx.x, tid = threadIdx.x;
  int2 me = metaE[t];
  float2 sc = metaS[t];
  size_t s0 = (size_t)(base[me.x] + metaP[t * 2 + 0]) * DMODEL;
  size_t s1 = (size_t)(base[me.y] + metaP[t * 2 + 1]) * DMODEL;
  float4 a = ((const float4*)(xmid + (size_t)t * DMODEL))[tid];
  float4 y0a = ((const float4*)(yv + s0))[tid];
  float4 y0b = ((const float4*)(yv2 + s0))[tid];
  float4 y1a = ((const float4*)(yv + s1))[tid];
  float4 y1b = ((const float4*)(yv2 + s1))[tid];
  float4 o;
  o.x = a.x + sc.x * (y0a.x + y0b.x) + sc.y * (y1a.x + y1b.x);
  o.y = a.y + sc.x * (y0a.y + y0b.y) + sc.y * (y1a.y + y1b.y);
  o.z = a.z + sc.x * (y0a.z + y0b.z) + sc.y * (y1a.z + y1b.z);
  o.w = a.w + sc.x * (y0a.w + y0b.w) + sc.y * (y1a.w + y1b.w);
  ((float4*)(out + (size_t)t * DMODEL))[tid] = o;
}

// ---------------------------------------------------------------------------
extern "C" void kernel_launch(void* const* d_in, const int* in_sizes, int n_in,
                              void* d_out, int out_size, void* d_ws, size_t ws_size,
                              hipStream_t stream) {
  (void)in_sizes; (void)n_in; (void)out_size; (void)ws_size;
  const float* x    = (const float*)d_in[0];
  const int*   am   = (const int*)d_in[1];
  const float* anw  = (const float*)d_in[2];
  const float* wq   = (const float*)d_in[3];
  const float* wk   = (const float*)d_in[4];
  const float* wv   = (const float*)d_in[5];
  const float* wo   = (const float*)d_in[6];
  const float* mnw  = (const float*)d_in[7];
  const float* rw   = (const float*)d_in[8];
  const float* w1   = (const float*)d_in[9];
  const float* b1   = (const float*)d_in[10];
  const float* w2   = (const float*)d_in[11];
  const float* b2   = (const float*)d_in[12];
  float* out = (float*)d_out;
  char* ws = (char*)d_ws;

  f16* wqkvT = (f16*)(ws + OFF_WQKVT);
  f16* woT   = (f16*)(ws + OFF_WOT);
  f16* w1T   = (f16*)(ws + OFF_W1T);
  f16* w2T   = (f16*)(ws + OFF_W2T);
  f16* hattn = (f16*)(ws + OFF_HATTN);
  f16* qb    = (f16*)(ws + OFF_Q);
  f16* kb    = (f16*)(ws + OFF_K);
  f16* vtb   = (f16*)(ws + OFF_VT);
  f16* oc    = (f16*)(ws + OFF_OC);
  float* xmid = (float*)(ws + OFF_XMID);
  f16* hmlp  = (f16*)(ws + OFF_HMLP);
  f16* hid   = (f16*)(ws + OFF_HID);
  float* y   = (float*)(ws + OFF_Y);
  float* y2  = (float*)(ws + OFF_Y2);
  int* list  = (int*)(ws + OFF_LIST);
  int2* metaE = (int2*)(ws + OFF_METAE);
  int* metaP  = (int*)(ws + OFF_METAP);
  float2* metaS = (float2*)(ws + OFF_METAS);
  float* bpsum = (float*)(ws + OFF_BPSUM);
  int* cnt   = (int*)(ws + OFF_CNT);
  int* base  = (int*)(ws + OFF_BASE);

  transpose_cast_kernel<<<dim3(16, 16, 1), 256, 0, stream>>>(wq, wqkvT, 1024, 1024);
  transpose_cast_kernel<<<dim3(16, 16, 1), 256, 0, stream>>>(wk, wqkvT + 1024 * 1024, 1024, 1024);
  transpose_cast_kernel<<<dim3(16, 16, 1), 256, 0, stream>>>(wv, wqkvT + 2 * 1024 * 1024, 1024, 1024);
  transpose_cast_kernel<<<dim3(16, 16, 1), 256, 0, stream>>>(wo, woT, 1024, 1024);
  transpose_cast_kernel<<<dim3(64, 16, 8), 256, 0, stream>>>(w1, w1T, 1024, 4096);
  transpose_cast_kernel<<<dim3(16, 64, 8), 256, 0, stream>>>(w2, w2T, 4096, 1024);

  rmsnorm_kernel<<<NTOK, 256, 0, stream>>>(x, anw, hattn);
  gemm_qkv_kernel<<<dim3(24, 32), 256, 0, stream>>>(hattn, wqkvT, qb, kb, vtb);
  attn_kernel<<<dim3(32, 32), 256, 0, stream>>>(qb, kb, vtb, am, oc);
  gemm_o_kernel<<<dim3(8, 32), 256, 0, stream>>>(oc, woT, x, xmid);
  rmsnorm_kernel<<<NTOK, 256, 0, stream>>>(xmid, mnw, hmlp);
  router_kernel<<<1024, 256, 0, stream>>>(xmid, mnw, rw, metaE, metaS, bpsum);
  scatter_kernel<<<8, 256, 0, stream>>>(metaE, list, metaP, cnt);
  finalize_kernel<<<1, 256, 0, stream>>>(cnt, bpsum, base, out + (size_t)NTOK * DMODEL);
  gemm_moe1_kernel<<<dim3(32, 32, 8), 256, 0, stream>>>(hmlp, w1T, b1, cnt, base, list, hid);
  gemm_moe2_kernel<<<dim3(8, 32, 16), 256, 0, stream>>>(hid, w2T, b2, cnt, base, y, y2);
  combine_kernel<<<NTOK, 256, 0, stream>>>(xmid, y, y2, metaE, metaP, metaS, base, out);
}

// Round 5
// 814.362 us; speedup vs baseline: 1.2186x; 1.0192x over previous
//
#include <hip/hip_runtime.h>

// ---------------------------------------------------------------------------
// PraxisBlock: rmsnorm -> QKV -> causal MHA -> O+residual -> rmsnorm ->
//              router top2/8 -> gathered expert FFN (gelu) -> combine
// All GEMMs: fp16 MFMA (v_mfma_f32_16x16x32_f16), fp32 accumulate.
// R1: router restructured — no global atomics (was 515us of XCD ping-pong).
// R2: attention re-tiled 64 q-rows/block, 1024 blocks, 32KB LDS.
// R3: XOR-swizzled LDS in gemm128 + split-K x2 for moe2.  [851us]
// R4/R5/R6 (ALL REVERTED): 256^2 tile / dbuf / counted-vmcnt pipelines all
//     land 194-201us on moe1 vs R3's 146us. 128^2 + 2-barrier + ~3 blocks/CU
//     is the measured optimum for these K=1024 gathered GEMMs (matches guide
//     tile-space: 128^2=912 > 256^2=792 TF at the 2-barrier structure).
// R7: vectorized transpose_cast (float4 in / f16x4 out, 64x64 tiles). [830us]
// R8: attention triangular load-balance fold: block (bh, qy) processes BOTH
//     q-tiles qy and 31-qy -> every block does exactly 33 K-tile steps
//     (was 1..32, makespan set by qt=31 stragglers while qt=0 CUs idled).
//     Grid (32,32) -> (32,16), 512 blocks, LDS reused across the two passes.
// ---------------------------------------------------------------------------

typedef _Float16 f16;
typedef _Float16 f16x8 __attribute__((ext_vector_type(8)));
typedef _Float16 f16x4v __attribute__((ext_vector_type(4)));
typedef float f32x4 __attribute__((ext_vector_type(4)));

#define DMODEL 1024
#define NHEAD  16
#define HDIM   64
#define NEXP   8
#define DFFN   4096
#define NBATCH 2
#define NSEQ   2048
#define NTOK   4096   // NBATCH*NSEQ
#define NPAIR  8192   // NTOK*2

// ---- workspace byte offsets (all 256-aligned) ----
#define OFF_WQKVT  0ull                  // 3*1024*1024 f16
#define OFF_WOT    6291456ull            // 1024*1024 f16
#define OFF_W1T    8388608ull            // 8*4096*1024 f16
#define OFF_W2T    75497472ull           // 8*1024*4096 f16
#define OFF_HATTN  142606336ull          // 4096*1024 f16   (dead after gemm_o; y2 reuses)
#define OFF_Q      150994944ull          // 32*2048*64 f16
#define OFF_K      159383552ull
#define OFF_VT     167772160ull
#define OFF_OC     176160768ull          // 4096*1024 f16
#define OFF_XMID   184549376ull          // 4096*1024 f32
#define OFF_HMLP   201326592ull          // 4096*1024 f16
#define OFF_HID    209715200ull          // 8192*4096 f16
#define OFF_Y      276824064ull          // 8192*1024 f32 (split-K half 0, +bias)
#define OFF_Y2     OFF_HATTN             // 8192*1024 f32 (split-K half 1) — hattn/q/k/vt dead by then
#define OFF_LIST   310378496ull          // 8*4096 int
#define OFF_METAE  310509568ull          // 4096 int2
#define OFF_METAP  310542336ull          // 4096 int2
#define OFF_METAS  310575104ull          // 4096 float2
#define OFF_BPSUM  310607872ull          // 1024*8 float (per-block prob sums)
#define OFF_CNT    310640640ull          // 8 int
#define OFF_PSUM   310640704ull          // 8 float
#define OFF_BASE   310640768ull          // 9 int

__device__ __forceinline__ void ldsAsync16(const void* g, void* l) {
  __builtin_amdgcn_global_load_lds((const __attribute__((address_space(1))) void*)g,
                                   (__attribute__((address_space(3))) void*)l, 16, 0, 0);
}

// ---------------- transpose + cast fp32[R][C] -> fp16[C][R] ----------------
// R7: 64x64 tile, 256 threads. Reads float4 (16B/lane), writes f16x4
// (8B/lane, 128B contiguous per 16-lane group). LDS [64][65].
__global__ __launch_bounds__(256) void transpose_cast_kernel(
    const float* __restrict__ src, f16* __restrict__ dst, int R, int C) {
  __shared__ float tile[64][65];
  const size_t zoff = (size_t)blockIdx.z * R * C;
  src += zoff; dst += zoff;
  int c0 = blockIdx.x * 64, r0 = blockIdx.y * 64;
  int tid = threadIdx.x;
  int c4 = tid & 15, rr = tid >> 4;   // read: 16 float4-cols x 16 rows
#pragma unroll
  for (int i = 0; i < 4; i++) {
    int row = rr + i * 16;
    float4 v = *(const float4*)&src[(size_t)(r0 + row) * C + c0 + c4 * 4];
    tile[row][c4 * 4 + 0] = v.x;
    tile[row][c4 * 4 + 1] = v.y;
    tile[row][c4 * 4 + 2] = v.z;
    tile[row][c4 * 4 + 3] = v.w;
  }
  __syncthreads();
  int r4 = tid & 15, cc = tid >> 4;   // write: 16 f16x4 r-chunks x 16 cols
#pragma unroll
  for (int i = 0; i < 4; i++) {
    int col = cc + i * 16;
    f16x4v o;
    o[0] = (f16)tile[r4 * 4 + 0][col];
    o[1] = (f16)tile[r4 * 4 + 1][col];
    o[2] = (f16)tile[r4 * 4 + 2][col];
    o[3] = (f16)tile[r4 * 4 + 3][col];
    *(f16x4v*)&dst[(size_t)(c0 + col) * R + r0 + r4 * 4] = o;
  }
}

// ---------------- rmsnorm fp32 -> fp16 ----------------
__global__ void rmsnorm_kernel(const float* __restrict__ x, const float* __restrict__ w,
                               f16* __restrict__ out) {
  int t = blockIdx.x, tid = threadIdx.x;
  float4 v = ((const float4*)(x + (size_t)t * DMODEL))[tid];
  float ss = v.x * v.x + v.y * v.y + v.z * v.z + v.w * v.w;
#pragma unroll
  for (int o = 32; o > 0; o >>= 1) ss += __shfl_down(ss, o);
  __shared__ float red[4];
  if ((tid & 63) == 0) red[tid >> 6] = ss;
  __syncthreads();
  float tot = red[0] + red[1] + red[2] + red[3];
  float rstd = rsqrtf(tot / (float)DMODEL + 1e-6f);
  float4 wv = ((const float4*)w)[tid];
  f16x4v o4;
  o4[0] = (f16)(v.x * rstd * wv.x);
  o4[1] = (f16)(v.y * rstd * wv.y);
  o4[2] = (f16)(v.z * rstd * wv.z);
  o4[3] = (f16)(v.w * rstd * wv.w);
  *(f16x4v*)(out + (size_t)t * DMODEL + tid * 4) = o4;
}

// ---------------- shared 128x128xK MFMA core (XOR-swizzled LDS) ----------
// R3 form: stage -> barrier -> compute, two __syncthreads per K-tile. The
// co-resident blocks (32KB LDS -> ~3 blocks/CU) hide the barrier drain.
// Staging contract: callers must point lane (kc=lane&7, rs=lane>>3) at global
// column chunk (kc ^ rs)*8 of its row, NOT kc*8. LDS[row][c] then holds global
// chunk c^(row&7); fragment reads below un-swizzle with j^(row&7).
template <class EPI>
__device__ __forceinline__ void gemm128(const f16* aP0, const f16* aP1, const f16* aP2, const f16* aP3,
                                        const f16* bP0, const f16* bP1, const f16* bP2, const f16* bP3,
                                        int K, EPI epi) {
  __shared__ __align__(16) f16 sA[128 * 64];
  __shared__ __align__(16) f16 sB[128 * 64];
  const int tid = threadIdx.x;
  const int lane = tid & 63, wave = tid >> 6;
  const int wm = (wave >> 1) * 64, wn = (wave & 1) * 64;
  const int q4 = lane >> 4, l15 = lane & 15;
  const int sw = lane & 7;  // == l15 & 7 == row&7 for fragment rows
  const f16* aP[4] = {aP0, aP1, aP2, aP3};
  const f16* bP[4] = {bP0, bP1, bP2, bP3};
  f32x4 zero = {0.f, 0.f, 0.f, 0.f};
  f32x4 acc[4][4];
#pragma unroll
  for (int i = 0; i < 4; i++)
#pragma unroll
    for (int j = 0; j < 4; j++) acc[i][j] = zero;

  for (int k0 = 0; k0 < K; k0 += 64) {
    __syncthreads();
#pragma unroll
    for (int i = 0; i < 4; i++) {
      ldsAsync16(aP[i] + k0, &sA[(i * 4 + wave) * 512]);
      ldsAsync16(bP[i] + k0, &sB[(i * 4 + wave) * 512]);
    }
    __syncthreads();
#pragma unroll
    for (int kk = 0; kk < 2; kk++) {
      f16x8 af[4], bf[4];
      int jx = ((kk * 4 + q4) ^ sw) * 8;
#pragma unroll
      for (int mi = 0; mi < 4; mi++)
        af[mi] = *(const f16x8*)&sA[(wm + mi * 16 + l15) * 64 + jx];
#pragma unroll
      for (int ni = 0; ni < 4; ni++)
        bf[ni] = *(const f16x8*)&sB[(wn + ni * 16 + l15) * 64 + jx];
#pragma unroll
      for (int mi = 0; mi < 4; mi++)
#pragma unroll
        for (int ni = 0; ni < 4; ni++)
          acc[mi][ni] = __builtin_amdgcn_mfma_f32_16x16x32_f16(af[mi], bf[ni], acc[mi][ni], 0, 0, 0);
    }
  }
#pragma unroll
  for (int mi = 0; mi < 4; mi++)
#pragma unroll
    for (int ni = 0; ni < 4; ni++)
#pragma unroll
      for (int r = 0; r < 4; r++)
        epi(wm + mi * 16 + q4 * 4 + r, wn + ni * 16 + l15, acc[mi][ni][r]);
}

// ---------------- QKV projection (N=3072 stacked) ----------------
__global__ __launch_bounds__(256, 2) void gemm_qkv_kernel(
    const f16* __restrict__ hA, const f16* __restrict__ wT,
    f16* __restrict__ qb, f16* __restrict__ kb, f16* __restrict__ vtb) {
  int mt = blockIdx.y, nt = blockIdx.x;
  int tid = threadIdx.x, lane = tid & 63, wave = tid >> 6;
  int kc = lane & 7, rs = lane >> 3;
  int kcs = (kc ^ rs) * 8;  // swizzled column chunk
  const f16 *a[4], *b[4];
#pragma unroll
  for (int i = 0; i < 4; i++) {
    int row = i * 32 + wave * 8 + rs;
    a[i] = hA + (size_t)(mt * 128 + row) * DMODEL + kcs;
    b[i] = wT + (size_t)(nt * 128 + row) * DMODEL + kcs;
  }
  int mB = mt * 128, nB = nt * 128;
  gemm128(a[0], a[1], a[2], a[3], b[0], b[1], b[2], b[3], DMODEL,
    [&](int r, int c, float v) {
      int m = mB + r, n = nB + c;
      int mat = n >> 10, nn = n & 1023;
      int h = nn >> 6, d = nn & 63;
      int bI = m >> 11, s = m & 2047;
      int bh = bI * NHEAD + h;
      f16 hv = (f16)v;
      if (mat == 0)      qb[((size_t)bh * NSEQ + s) * HDIM + d] = hv;
      else if (mat == 1) kb[((size_t)bh * NSEQ + s) * HDIM + d] = hv;
      else               vtb[((size_t)bh * HDIM + d) * NSEQ + s] = hv;
    });
}

// ---------------- O projection + residual ----------------
__global__ __launch_bounds__(256, 2) void gemm_o_kernel(
    const f16* __restrict__ oc, const f16* __restrict__ woT,
    const float* __restrict__ xin, float* __restrict__ xmid) {
  int mt = blockIdx.y, nt = blockIdx.x;
  int tid = threadIdx.x, lane = tid & 63, wave = tid >> 6;
  int kc = lane & 7, rs = lane >> 3;
  int kcs = (kc ^ rs) * 8;
  const f16 *a[4], *b[4];
#pragma unroll
  for (int i = 0; i < 4; i++) {
    int row = i * 32 + wave * 8 + rs;
    a[i] = oc + (size_t)(mt * 128 + row) * DMODEL + kcs;
    b[i] = woT + (size_t)(nt * 128 + row) * DMODEL + kcs;
  }
  int mB = mt * 128, nB = nt * 128;
  gemm128(a[0], a[1], a[2], a[3], b[0], b[1], b[2], b[3], DMODEL,
    [&](int r, int c, float v) {
      size_t idx = (size_t)(mB + r) * DMODEL + nB + c;
      xmid[idx] = xin[idx] + v;
    });
}

// ---------------- MoE expert GEMM 1: h -> gelu(h*w1+b1) ----------------
__global__ __launch_bounds__(256, 2) void gemm_moe1_kernel(
    const f16* __restrict__ hM, const f16* __restrict__ w1T, const float* __restrict__ b1,
    const int* __restrict__ cnt, const int* __restrict__ base, const int* __restrict__ list,
    f16* __restrict__ hid) {
  int e = blockIdx.z, mt = blockIdx.y, nt = blockIdx.x;
  int c_e = cnt[e];
  if (mt * 128 >= c_e) return;
  int tid = threadIdx.x, lane = tid & 63, wave = tid >> 6;
  int kc = lane & 7, rs = lane >> 3;
  int kcs = (kc ^ rs) * 8;
  const f16 *a[4], *b[4];
#pragma unroll
  for (int i = 0; i < 4; i++) {
    int row = i * 32 + wave * 8 + rs;
    int rr = mt * 128 + row; rr = rr < c_e ? rr : c_e - 1;
    int tok = list[e * NTOK + rr];
    a[i] = hM + (size_t)tok * DMODEL + kcs;
    b[i] = w1T + ((size_t)e * DFFN + nt * 128 + row) * DMODEL + kcs;
  }
  int rowBase = base[e] + mt * 128, nB = nt * 128, mLoc = mt * 128;
  gemm128(a[0], a[1], a[2], a[3], b[0], b[1], b[2], b[3], DMODEL,
    [&](int r, int c, float v) {
      if (mLoc + r < c_e) {
        float v2 = v + b1[e * DFFN + nB + c];
        float u = 1.5957691216057308f * (v2 + 0.044715f * v2 * v2 * v2); // 2*0.79788456*
        float th = 1.f - 2.f / (__expf(u) + 1.f);                        // tanh
        hid[(size_t)(rowBase + r) * DFFN + nB + c] = (f16)(0.5f * v2 * (1.f + th));
      }
    });
}

// ---------------- MoE expert GEMM 2: hid*w2+b2 -> y (split-K x2) ----------
__global__ __launch_bounds__(256, 2) void gemm_moe2_kernel(
    const f16* __restrict__ hid, const f16* __restrict__ w2T, const float* __restrict__ b2,
    const int* __restrict__ cnt, const int* __restrict__ base,
    float* __restrict__ y, float* __restrict__ y2) {
  int z = blockIdx.z, e = z >> 1, kh = z & 1;
  int mt = blockIdx.y, nt = blockIdx.x;
  int c_e = cnt[e];
  if (mt * 128 >= c_e) return;
  int tid = threadIdx.x, lane = tid & 63, wave = tid >> 6;
  int kc = lane & 7, rs = lane >> 3;
  int kcs = (kc ^ rs) * 8 + kh * 2048;
  int bse = base[e];
  const f16 *a[4], *b[4];
#pragma unroll
  for (int i = 0; i < 4; i++) {
    int row = i * 32 + wave * 8 + rs;
    int rr = mt * 128 + row; rr = rr < c_e ? rr : c_e - 1;
    a[i] = hid + (size_t)(bse + rr) * DFFN + kcs;
    b[i] = w2T + ((size_t)e * DMODEL + nt * 128 + row) * DFFN + kcs;
  }
  int nB = nt * 128, mLoc = mt * 128;
  float* yo = kh ? y2 : y;
  gemm128(a[0], a[1], a[2], a[3], b[0], b[1], b[2], b[3], 2048,
    [&](int r, int c, float v) {
      if (mLoc + r < c_e) {
        float bias = kh ? 0.f : b2[e * DMODEL + nB + c];
        yo[(size_t)(bse + mLoc + r) * DMODEL + nB + c] = v + bias;
      }
    });
}

// ---------------- flash attention (causal + key mask) ----------------
// R8: triangular fold — block (bh, qy) handles q-tiles qy AND 31-qy, so
// every block does exactly 33 K-tile steps (uniform makespan; was 1..32).
// Grid (32,16), 512 blocks. bh on blockIdx.x keeps head->XCD locality.
__global__ __launch_bounds__(256, 4) void attn_kernel(
    const f16* __restrict__ qb, const f16* __restrict__ kb, const f16* __restrict__ vtb,
    const int* __restrict__ amask, f16* __restrict__ oc) {
  int bh = blockIdx.x, qy = blockIdx.y;
  int bI = bh >> 4, h = bh & 15;
  int tid = threadIdx.x, lane = tid & 63, wave = tid >> 6;
  int q4 = lane >> 4, l15 = lane & 15;
  int kc = lane & 7, rs = lane >> 3;

  __shared__ __align__(16) f16 sQ[64 * 64];
  __shared__ __align__(16) f16 sK[64 * 64];
  __shared__ __align__(16) f16 sVT[64 * 64];
  __shared__ __align__(16) f16 sP[4][16 * 64];
  __shared__ int sMask[64];

  const f16* qBH = qb + (size_t)bh * NSEQ * HDIM;
  const f16* kBH = kb + (size_t)bh * NSEQ * HDIM;
  const f16* vBH = vtb + (size_t)bh * HDIM * NSEQ;
  f16* sPw = sP[wave];
  f32x4 zero = {0.f, 0.f, 0.f, 0.f};

  for (int pass = 0; pass < 2; pass++) {
    int qt = pass ? (31 - qy) : qy;
    int qbase = qt * 64;

    __syncthreads();  // prior pass done reading sQ before overwrite
#pragma unroll
    for (int i = 0; i < 2; i++) {
      int row = i * 32 + wave * 8 + rs;  // 0..63
      ldsAsync16(qBH + (size_t)(qbase + row) * HDIM + kc * 8, &sQ[(i * 4 + wave) * 512]);
    }

    f32x4 accO[4];
    float mrow[4], lrow[4];
#pragma unroll
    for (int j = 0; j < 4; j++) { accO[j] = zero; mrow[j] = -3.0e38f; lrow[j] = 0.f; }

    for (int kt = 0; kt <= qt; kt++) {
      int kb0 = kt * 64;
      bool diag = (kt == qt);
      __syncthreads();
#pragma unroll
      for (int i = 0; i < 2; i++) {
        int row = i * 32 + wave * 8 + rs;  // 0..63
        ldsAsync16(kBH + (size_t)(kb0 + row) * HDIM + kc * 8, &sK[(i * 4 + wave) * 512]);
        ldsAsync16(vBH + (size_t)row * NSEQ + kb0 + kc * 8, &sVT[(i * 4 + wave) * 512]);
      }
      if (tid < 64) sMask[tid] = amask[bI * NSEQ + kb0 + tid];
      __syncthreads();

      f32x4 accS[4];
#pragma unroll
      for (int j = 0; j < 4; j++) accS[j] = zero;
#pragma unroll
      for (int kk = 0; kk < 2; kk++) {
        f16x8 af = *(const f16x8*)&sQ[(wave * 16 + l15) * 64 + kk * 32 + q4 * 8];
        f16x8 bf[4];
#pragma unroll
        for (int nj = 0; nj < 4; nj++)
          bf[nj] = *(const f16x8*)&sK[(nj * 16 + l15) * 64 + kk * 32 + q4 * 8];
#pragma unroll
        for (int nj = 0; nj < 4; nj++)
          accS[nj] = __builtin_amdgcn_mfma_f32_16x16x32_f16(af, bf[nj], accS[nj], 0, 0, 0);
      }
      bool mok[4];
      int gk[4];
#pragma unroll
      for (int nj = 0; nj < 4; nj++) {
        gk[nj] = nj * 16 + l15;
        mok[nj] = sMask[gk[nj]] > 0;
      }
#pragma unroll
      for (int r = 0; r < 4; r++) {
        int lq = wave * 16 + q4 * 4 + r;  // local q row 0..63; global gq = qbase+lq
        float rm = -3.0e38f;
#pragma unroll
        for (int nj = 0; nj < 4; nj++) {
          float s = accS[nj][r] * 0.125f;
          bool ok = mok[nj] && (!diag || gk[nj] <= lq);
          s = ok ? s : -1.0e9f;
          accS[nj][r] = s;
          rm = fmaxf(rm, s);
        }
#pragma unroll
        for (int o = 1; o < 16; o <<= 1) rm = fmaxf(rm, __shfl_xor(rm, o));
        float mold = mrow[r];
        float mnew = fmaxf(mold, rm);
        float alpha = __expf(mold - mnew);
        float rsum = 0.f;
#pragma unroll
        for (int nj = 0; nj < 4; nj++) {
          float p = __expf(accS[nj][r] - mnew);
          rsum += p;
          sPw[(q4 * 4 + r) * 64 + nj * 16 + l15] = (f16)p;
        }
#pragma unroll
        for (int o = 1; o < 16; o <<= 1) rsum += __shfl_xor(rsum, o);
        lrow[r] = lrow[r] * alpha + rsum;
        mrow[r] = mnew;
#pragma unroll
        for (int dj = 0; dj < 4; dj++) accO[dj][r] *= alpha;
      }
      // PV (sP is per-wave private; compiler's lgkmcnt covers write->read)
#pragma unroll
      for (int kk = 0; kk < 2; kk++) {
        f16x8 pf = *(const f16x8*)&sPw[l15 * 64 + kk * 32 + q4 * 8];
        f16x8 vf[4];
#pragma unroll
        for (int dj = 0; dj < 4; dj++)
          vf[dj] = *(const f16x8*)&sVT[(dj * 16 + l15) * 64 + kk * 32 + q4 * 8];
#pragma unroll
        for (int dj = 0; dj < 4; dj++)
          accO[dj] = __builtin_amdgcn_mfma_f32_16x16x32_f16(pf, vf[dj], accO[dj], 0, 0, 0);
      }
    }
    // epilogue: divide by l, scatter to o_concat[token][h*64+d]
#pragma unroll
    for (int r = 0; r < 4; r++) {
      float inv = 1.f / lrow[r];
      int s = qbase + wave * 16 + q4 * 4 + r;
      size_t rowoff = ((size_t)bI * NSEQ + s) * DMODEL + h * HDIM;
#pragma unroll
      for (int dj = 0; dj < 4; dj++)
        oc[rowoff + dj * 16 + l15] = (f16)(accO[dj][r] * inv);
    }
  }
}

// ---------------- router: wave-per-token, NO global atomics ----------------
__global__ __launch_bounds__(256) void router_kernel(
    const float* __restrict__ xmid, const float* __restrict__ normw,
    const float* __restrict__ rw, int2* __restrict__ metaE,
    float2* __restrict__ metaS, float* __restrict__ blockpsum) {
  int wave = threadIdx.x >> 6, lane = threadIdx.x & 63;
  int t = blockIdx.x * 4 + wave;
  __shared__ float sprob[4][8];

  const float4* xr = (const float4*)(xmid + (size_t)t * DMODEL);
  const float4* wr = (const float4*)normw;
  float4 v[4];
  float ss = 0.f;
#pragma unroll
  for (int i = 0; i < 4; i++) {
    v[i] = xr[lane * 4 + i];
    ss += v[i].x * v[i].x + v[i].y * v[i].y + v[i].z * v[i].z + v[i].w * v[i].w;
  }
#pragma unroll
  for (int o = 32; o > 0; o >>= 1) ss += __shfl_xor(ss, o);
  float rstd = rsqrtf(ss / (float)DMODEL + 1e-6f);

  float part[8] = {0, 0, 0, 0, 0, 0, 0, 0};
#pragma unroll
  for (int i = 0; i < 4; i++) {
    float4 wv = wr[lane * 4 + i];
    float hv[4] = {v[i].x * rstd * wv.x, v[i].y * rstd * wv.y,
                   v[i].z * rstd * wv.z, v[i].w * rstd * wv.w};
#pragma unroll
    for (int j = 0; j < 4; j++) {
      int row = lane * 16 + i * 4 + j;
      const float4* rr = (const float4*)(rw + (size_t)row * NEXP);
      float4 a = rr[0], b = rr[1];
      part[0] += hv[j] * a.x; part[1] += hv[j] * a.y;
      part[2] += hv[j] * a.z; part[3] += hv[j] * a.w;
      part[4] += hv[j] * b.x; part[5] += hv[j] * b.y;
      part[6] += hv[j] * b.z; part[7] += hv[j] * b.w;
    }
  }
#pragma unroll
  for (int o = 1; o < 64; o <<= 1)
#pragma unroll
    for (int e = 0; e < 8; e++) part[e] += __shfl_xor(part[e], o);

  if (lane == 0) {
    float mx = -3.0e38f;
#pragma unroll
    for (int e = 0; e < 8; e++) mx = fmaxf(mx, part[e]);
    float probs[8], sum = 0.f;
#pragma unroll
    for (int e = 0; e < 8; e++) { probs[e] = __expf(part[e] - mx); sum += probs[e]; }
    float inv = 1.f / sum;
#pragma unroll
    for (int e = 0; e < 8; e++) { probs[e] *= inv; sprob[wave][e] = probs[e]; }
    int e0 = 0;
#pragma unroll
    for (int e = 1; e < 8; e++) if (part[e] > part[e0]) e0 = e;
    int e1 = (e0 == 0) ? 1 : 0;
#pragma unroll
    for (int e = 0; e < 8; e++) if (e != e0 && part[e] > part[e1]) e1 = e;
    metaE[t] = make_int2(e0, e1);
    metaS[t] = make_float2(probs[e0], probs[e1]);
  }
  __syncthreads();
  if (threadIdx.x < 8)
    blockpsum[blockIdx.x * 8 + threadIdx.x] =
        sprob[0][threadIdx.x] + sprob[1][threadIdx.x] +
        sprob[2][threadIdx.x] + sprob[3][threadIdx.x];
}

// ---------------- scatter: one block per expert, deterministic prefix sum ----
__global__ __launch_bounds__(256) void scatter_kernel(
    const int2* __restrict__ metaE, int* __restrict__ list,
    int* __restrict__ metaP, int* __restrict__ cnt) {
  int e = blockIdx.x;
  int tid = threadIdx.x, lane = tid & 63, w = tid >> 6;
  __shared__ int wsum[4];
  __shared__ int sbase;
  if (tid == 0) sbase = 0;
  __syncthreads();
  for (int c = 0; c < NTOK; c += 256) {
    int tok = c + tid;
    int2 me = metaE[tok];
    bool m0 = (me.x == e), m1 = (me.y == e);
    bool m = m0 || m1;
    unsigned long long mask = __ballot(m);
    int wpre = __popcll(mask & ((1ull << lane) - 1ull));
    if (lane == 0) wsum[w] = __popcll(mask);
    __syncthreads();
    int base0 = sbase;
    int pre = wpre;
    for (int i = 0; i < w; i++) pre += wsum[i];
    int tot = wsum[0] + wsum[1] + wsum[2] + wsum[3];
    if (m) {
      int pos = base0 + pre;
      list[e * NTOK + base0 + pre] = tok;
      metaP[tok * 2 + (m0 ? 0 : 1)] = pos;
    }
    __syncthreads();
    if (tid == 0) sbase = base0 + tot;
  }
  __syncthreads();
  if (tid == 0) cnt[e] = sbase;
}

// ---------------- finalize: base offsets + balancing loss + counts ----------
__global__ __launch_bounds__(256) void finalize_kernel(
    const int* __restrict__ cnt, const float* __restrict__ blockpsum,
    int* __restrict__ base, float* __restrict__ out_tail) {
  int tid = threadIdx.x;
  int e = tid & 7, slot = tid >> 3;  // 32 slots per expert
  float acc = 0.f;
  for (int i = slot; i < 1024; i += 32) acc += blockpsum[i * 8 + e];
  __shared__ float red[256];
  red[tid] = acc;
  __syncthreads();
  for (int s = 128; s >= 8; s >>= 1) {
    if (tid < s) red[tid] += red[tid + s];
    __syncthreads();
  }
  if (tid == 0) {
    int b = 0;
#pragma unroll
    for (int i = 0; i < 8; i++) { base[i] = b; b += cnt[i]; }
    base[8] = b;
    float loss = 0.f;
#pragma unroll
    for (int i = 0; i < 8; i++)
      loss += ((float)cnt[i] / (float)NPAIR) * (red[i] / (float)NTOK);
    out_tail[0] = loss * (float)NEXP;
#pragma unroll
    for (int i = 0; i < 8; i++) out_tail[1 + i] = (float)cnt[i];
  }
}

// ---------------- final combine (sums split-K halves) ----------------
__global__ void combine_kernel(const float* __restrict__ xmid, const float* __restrict__ yv,
                               const float* __restrict__ yv2,
                               const int2* __restrict__ metaE, const int* __restrict__ metaP,
                               const float2* __restrict__ metaS,
                               const int* __restrict__ base, float* __restrict__ out) {
  int t = blockIdx.x, tid = threadIdx.x;
  int2 me = metaE[t];
  float2 sc = metaS[t];
  size_t s0 = (size_t)(base[me.x] + metaP[t * 2 + 0]) * DMODEL;
  size_t s1 = (size_t)(base[me.y] + metaP[t * 2 + 1]) * DMODEL;
  float4 a = ((const float4*)(xmid + (size_t)t * DMODEL))[tid];
  float4 y0a = ((const float4*)(yv + s0))[tid];
  float4 y0b = ((const float4*)(yv2 + s0))[tid];
  float4 y1a = ((const float4*)(yv + s1))[tid];
  float4 y1b = ((const float4*)(yv2 + s1))[tid];
  float4 o;
  o.x = a.x + sc.x * (y0a.x + y0b.x) + sc.y * (y1a.x + y1b.x);
  o.y = a.y + sc.x * (y0a.y + y0b.y) + sc.y * (y1a.y + y1b.y);
  o.z = a.z + sc.x * (y0a.z + y0b.z) + sc.y * (y1a.z + y1b.z);
  o.w = a.w + sc.x * (y0a.w + y0b.w) + sc.y * (y1a.w + y1b.w);
  ((float4*)(out + (size_t)t * DMODEL))[tid] = o;
}

// ---------------------------------------------------------------------------
extern "C" void kernel_launch(void* const* d_in, const int* in_sizes, int n_in,
                              void* d_out, int out_size, void* d_ws, size_t ws_size,
                              hipStream_t stream) {
  (void)in_sizes; (void)n_in; (void)out_size; (void)ws_size;
  const float* x    = (const float*)d_in[0];
  const int*   am   = (const int*)d_in[1];
  const float* anw  = (const float*)d_in[2];
  const float* wq   = (const float*)d_in[3];
  const float* wk   = (const float*)d_in[4];
  const float* wv   = (const float*)d_in[5];
  const float* wo   = (const float*)d_in[6];
  const float* mnw  = (const float*)d_in[7];
  const float* rw   = (const float*)d_in[8];
  const float* w1   = (const float*)d_in[9];
  const float* b1   = (const float*)d_in[10];
  const float* w2   = (const float*)d_in[11];
  const float* b2   = (const float*)d_in[12];
  float* out = (float*)d_out;
  char* ws = (char*)d_ws;

  f16* wqkvT = (f16*)(ws + OFF_WQKVT);
  f16* woT   = (f16*)(ws + OFF_WOT);
  f16* w1T   = (f16*)(ws + OFF_W1T);
  f16* w2T   = (f16*)(ws + OFF_W2T);
  f16* hattn = (f16*)(ws + OFF_HATTN);
  f16* qb    = (f16*)(ws + OFF_Q);
  f16* kb    = (f16*)(ws + OFF_K);
  f16* vtb   = (f16*)(ws + OFF_VT);
  f16* oc    = (f16*)(ws + OFF_OC);
  float* xmid = (float*)(ws + OFF_XMID);
  f16* hmlp  = (f16*)(ws + OFF_HMLP);
  f16* hid   = (f16*)(ws + OFF_HID);
  float* y   = (float*)(ws + OFF_Y);
  float* y2  = (float*)(ws + OFF_Y2);
  int* list  = (int*)(ws + OFF_LIST);
  int2* metaE = (int2*)(ws + OFF_METAE);
  int* metaP  = (int*)(ws + OFF_METAP);
  float2* metaS = (float2*)(ws + OFF_METAS);
  float* bpsum = (float*)(ws + OFF_BPSUM);
  int* cnt   = (int*)(ws + OFF_CNT);
  int* base  = (int*)(ws + OFF_BASE);

  transpose_cast_kernel<<<dim3(16, 16, 1), 256, 0, stream>>>(wq, wqkvT, 1024, 1024);
  transpose_cast_kernel<<<dim3(16, 16, 1), 256, 0, stream>>>(wk, wqkvT + 1024 * 1024, 1024, 1024);
  transpose_cast_kernel<<<dim3(16, 16, 1), 256, 0, stream>>>(wv, wqkvT + 2 * 1024 * 1024, 1024, 1024);
  transpose_cast_kernel<<<dim3(16, 16, 1), 256, 0, stream>>>(wo, woT, 1024, 1024);
  transpose_cast_kernel<<<dim3(64, 16, 8), 256, 0, stream>>>(w1, w1T, 1024, 4096);
  transpose_cast_kernel<<<dim3(16, 64, 8), 256, 0, stream>>>(w2, w2T, 4096, 1024);

  rmsnorm_kernel<<<NTOK, 256, 0, stream>>>(x, anw, hattn);
  gemm_qkv_kernel<<<dim3(24, 32), 256, 0, stream>>>(hattn, wqkvT, qb, kb, vtb);
  attn_kernel<<<dim3(32, 16), 256, 0, stream>>>(qb, kb, vtb, am, oc);
  gemm_o_kernel<<<dim3(8, 32), 256, 0, stream>>>(oc, woT, x, xmid);
  rmsnorm_kernel<<<NTOK, 256, 0, stream>>>(xmid, mnw, hmlp);
  router_kernel<<<1024, 256, 0, stream>>>(xmid, mnw, rw, metaE, metaS, bpsum);
  scatter_kernel<<<8, 256, 0, stream>>>(metaE, list, metaP, cnt);
  finalize_kernel<<<1, 256, 0, stream>>>(cnt, bpsum, base, out + (size_t)NTOK * DMODEL);
  gemm_moe1_kernel<<<dim3(32, 32, 8), 256, 0, stream>>>(hmlp, w1T, b1, cnt, base, list, hid);
  gemm_moe2_kernel<<<dim3(8, 32, 16), 256, 0, stream>>>(hid, w2T, b2, cnt, base, y, y2);
  combine_kernel<<<NTOK, 256, 0, stream>>>(xmid, y, y2, metaE, metaP, metaS, base, out);
}

// Round 6
// 811.388 us; speedup vs baseline: 1.2231x; 1.0037x over previous
//
#include <hip/hip_runtime.h>

// ---------------------------------------------------------------------------
// PraxisBlock: rmsnorm -> QKV -> causal MHA -> O+residual -> rmsnorm ->
//              router top2/8 -> gathered expert FFN (gelu) -> combine
// All GEMMs: fp16 MFMA (v_mfma_f32_16x16x32_f16), fp32 accumulate.
// R1: router restructured — no global atomics (was 515us of XCD ping-pong).
// R2: attention re-tiled 64 q-rows/block, 1024 blocks, 32KB LDS.
// R3: XOR-swizzled LDS in gemm128 + split-K x2 for moe2.  [851us]
// R4/R5/R6 (ALL REVERTED): 256^2 tile / dbuf / counted-vmcnt pipelines all
//     land 194-201us on moe1 vs R3's 146us. 128^2 + 2-barrier + co-resident
//     blocks is the measured optimum for these K=1024 gathered GEMMs.
// R7: vectorized transpose_cast (float4 in / f16x4 out). [830us]
// R8: attention triangular fold (uniform 33 K-steps/block). [814us]
// R9: occupancy granule fix. Combined regs = 72 VGPR + 64 AGPR(acc) = 136;
//     64-reg HW granule rounds to 192 -> only 2 blocks/CU co-resident
//     (matches Occ 27.7%). __launch_bounds__(256,3) caps the allocator at
//     128 combined -> arch VGPR forced to 64 -> 4 blocks/CU, doubling the
//     cross-block overlap that is this structure's proven mechanism.
// ---------------------------------------------------------------------------

typedef _Float16 f16;
typedef _Float16 f16x8 __attribute__((ext_vector_type(8)));
typedef _Float16 f16x4v __attribute__((ext_vector_type(4)));
typedef float f32x4 __attribute__((ext_vector_type(4)));

#define DMODEL 1024
#define NHEAD  16
#define HDIM   64
#define NEXP   8
#define DFFN   4096
#define NBATCH 2
#define NSEQ   2048
#define NTOK   4096   // NBATCH*NSEQ
#define NPAIR  8192   // NTOK*2

// ---- workspace byte offsets (all 256-aligned) ----
#define OFF_WQKVT  0ull                  // 3*1024*1024 f16
#define OFF_WOT    6291456ull            // 1024*1024 f16
#define OFF_W1T    8388608ull            // 8*4096*1024 f16
#define OFF_W2T    75497472ull           // 8*1024*4096 f16
#define OFF_HATTN  142606336ull          // 4096*1024 f16   (dead after gemm_o; y2 reuses)
#define OFF_Q      150994944ull          // 32*2048*64 f16
#define OFF_K      159383552ull
#define OFF_VT     167772160ull
#define OFF_OC     176160768ull          // 4096*1024 f16
#define OFF_XMID   184549376ull          // 4096*1024 f32
#define OFF_HMLP   201326592ull          // 4096*1024 f16
#define OFF_HID    209715200ull          // 8192*4096 f16
#define OFF_Y      276824064ull          // 8192*1024 f32 (split-K half 0, +bias)
#define OFF_Y2     OFF_HATTN             // 8192*1024 f32 (split-K half 1) — hattn/q/k/vt dead by then
#define OFF_LIST   310378496ull          // 8*4096 int
#define OFF_METAE  310509568ull          // 4096 int2
#define OFF_METAP  310542336ull          // 4096 int2
#define OFF_METAS  310575104ull          // 4096 float2
#define OFF_BPSUM  310607872ull          // 1024*8 float (per-block prob sums)
#define OFF_CNT    310640640ull          // 8 int
#define OFF_PSUM   310640704ull          // 8 float
#define OFF_BASE   310640768ull          // 9 int

__device__ __forceinline__ void ldsAsync16(const void* g, void* l) {
  __builtin_amdgcn_global_load_lds((const __attribute__((address_space(1))) void*)g,
                                   (__attribute__((address_space(3))) void*)l, 16, 0, 0);
}

// ---------------- transpose + cast fp32[R][C] -> fp16[C][R] ----------------
// R7: 64x64 tile, 256 threads. Reads float4 (16B/lane), writes f16x4
// (8B/lane, 128B contiguous per 16-lane group). LDS [64][65].
__global__ __launch_bounds__(256) void transpose_cast_kernel(
    const float* __restrict__ src, f16* __restrict__ dst, int R, int C) {
  __shared__ float tile[64][65];
  const size_t zoff = (size_t)blockIdx.z * R * C;
  src += zoff; dst += zoff;
  int c0 = blockIdx.x * 64, r0 = blockIdx.y * 64;
  int tid = threadIdx.x;
  int c4 = tid & 15, rr = tid >> 4;   // read: 16 float4-cols x 16 rows
#pragma unroll
  for (int i = 0; i < 4; i++) {
    int row = rr + i * 16;
    float4 v = *(const float4*)&src[(size_t)(r0 + row) * C + c0 + c4 * 4];
    tile[row][c4 * 4 + 0] = v.x;
    tile[row][c4 * 4 + 1] = v.y;
    tile[row][c4 * 4 + 2] = v.z;
    tile[row][c4 * 4 + 3] = v.w;
  }
  __syncthreads();
  int r4 = tid & 15, cc = tid >> 4;   // write: 16 f16x4 r-chunks x 16 cols
#pragma unroll
  for (int i = 0; i < 4; i++) {
    int col = cc + i * 16;
    f16x4v o;
    o[0] = (f16)tile[r4 * 4 + 0][col];
    o[1] = (f16)tile[r4 * 4 + 1][col];
    o[2] = (f16)tile[r4 * 4 + 2][col];
    o[3] = (f16)tile[r4 * 4 + 3][col];
    *(f16x4v*)&dst[(size_t)(c0 + col) * R + r0 + r4 * 4] = o;
  }
}

// ---------------- rmsnorm fp32 -> fp16 ----------------
__global__ void rmsnorm_kernel(const float* __restrict__ x, const float* __restrict__ w,
                               f16* __restrict__ out) {
  int t = blockIdx.x, tid = threadIdx.x;
  float4 v = ((const float4*)(x + (size_t)t * DMODEL))[tid];
  float ss = v.x * v.x + v.y * v.y + v.z * v.z + v.w * v.w;
#pragma unroll
  for (int o = 32; o > 0; o >>= 1) ss += __shfl_down(ss, o);
  __shared__ float red[4];
  if ((tid & 63) == 0) red[tid >> 6] = ss;
  __syncthreads();
  float tot = red[0] + red[1] + red[2] + red[3];
  float rstd = rsqrtf(tot / (float)DMODEL + 1e-6f);
  float4 wv = ((const float4*)w)[tid];
  f16x4v o4;
  o4[0] = (f16)(v.x * rstd * wv.x);
  o4[1] = (f16)(v.y * rstd * wv.y);
  o4[2] = (f16)(v.z * rstd * wv.z);
  o4[3] = (f16)(v.w * rstd * wv.w);
  *(f16x4v*)(out + (size_t)t * DMODEL + tid * 4) = o4;
}

// ---------------- shared 128x128xK MFMA core (XOR-swizzled LDS) ----------
// R3 form: stage -> barrier -> compute, two __syncthreads per K-tile. The
// co-resident blocks hide the barrier drain.
// Staging contract: callers must point lane (kc=lane&7, rs=lane>>3) at global
// column chunk (kc ^ rs)*8 of its row, NOT kc*8. LDS[row][c] then holds global
// chunk c^(row&7); fragment reads below un-swizzle with j^(row&7).
template <class EPI>
__device__ __forceinline__ void gemm128(const f16* aP0, const f16* aP1, const f16* aP2, const f16* aP3,
                                        const f16* bP0, const f16* bP1, const f16* bP2, const f16* bP3,
                                        int K, EPI epi) {
  __shared__ __align__(16) f16 sA[128 * 64];
  __shared__ __align__(16) f16 sB[128 * 64];
  const int tid = threadIdx.x;
  const int lane = tid & 63, wave = tid >> 6;
  const int wm = (wave >> 1) * 64, wn = (wave & 1) * 64;
  const int q4 = lane >> 4, l15 = lane & 15;
  const int sw = lane & 7;  // == l15 & 7 == row&7 for fragment rows
  const f16* aP[4] = {aP0, aP1, aP2, aP3};
  const f16* bP[4] = {bP0, bP1, bP2, bP3};
  f32x4 zero = {0.f, 0.f, 0.f, 0.f};
  f32x4 acc[4][4];
#pragma unroll
  for (int i = 0; i < 4; i++)
#pragma unroll
    for (int j = 0; j < 4; j++) acc[i][j] = zero;

  for (int k0 = 0; k0 < K; k0 += 64) {
    __syncthreads();
#pragma unroll
    for (int i = 0; i < 4; i++) {
      ldsAsync16(aP[i] + k0, &sA[(i * 4 + wave) * 512]);
      ldsAsync16(bP[i] + k0, &sB[(i * 4 + wave) * 512]);
    }
    __syncthreads();
#pragma unroll
    for (int kk = 0; kk < 2; kk++) {
      f16x8 af[4], bf[4];
      int jx = ((kk * 4 + q4) ^ sw) * 8;
#pragma unroll
      for (int mi = 0; mi < 4; mi++)
        af[mi] = *(const f16x8*)&sA[(wm + mi * 16 + l15) * 64 + jx];
#pragma unroll
      for (int ni = 0; ni < 4; ni++)
        bf[ni] = *(const f16x8*)&sB[(wn + ni * 16 + l15) * 64 + jx];
#pragma unroll
      for (int mi = 0; mi < 4; mi++)
#pragma unroll
        for (int ni = 0; ni < 4; ni++)
          acc[mi][ni] = __builtin_amdgcn_mfma_f32_16x16x32_f16(af[mi], bf[ni], acc[mi][ni], 0, 0, 0);
    }
  }
#pragma unroll
  for (int mi = 0; mi < 4; mi++)
#pragma unroll
    for (int ni = 0; ni < 4; ni++)
#pragma unroll
      for (int r = 0; r < 4; r++)
        epi(wm + mi * 16 + q4 * 4 + r, wn + ni * 16 + l15, acc[mi][ni][r]);
}

// ---------------- QKV projection (N=3072 stacked) ----------------
__global__ __launch_bounds__(256, 3) void gemm_qkv_kernel(
    const f16* __restrict__ hA, const f16* __restrict__ wT,
    f16* __restrict__ qb, f16* __restrict__ kb, f16* __restrict__ vtb) {
  int mt = blockIdx.y, nt = blockIdx.x;
  int tid = threadIdx.x, lane = tid & 63, wave = tid >> 6;
  int kc = lane & 7, rs = lane >> 3;
  int kcs = (kc ^ rs) * 8;  // swizzled column chunk
  const f16 *a[4], *b[4];
#pragma unroll
  for (int i = 0; i < 4; i++) {
    int row = i * 32 + wave * 8 + rs;
    a[i] = hA + (size_t)(mt * 128 + row) * DMODEL + kcs;
    b[i] = wT + (size_t)(nt * 128 + row) * DMODEL + kcs;
  }
  int mB = mt * 128, nB = nt * 128;
  gemm128(a[0], a[1], a[2], a[3], b[0], b[1], b[2], b[3], DMODEL,
    [&](int r, int c, float v) {
      int m = mB + r, n = nB + c;
      int mat = n >> 10, nn = n & 1023;
      int h = nn >> 6, d = nn & 63;
      int bI = m >> 11, s = m & 2047;
      int bh = bI * NHEAD + h;
      f16 hv = (f16)v;
      if (mat == 0)      qb[((size_t)bh * NSEQ + s) * HDIM + d] = hv;
      else if (mat == 1) kb[((size_t)bh * NSEQ + s) * HDIM + d] = hv;
      else               vtb[((size_t)bh * HDIM + d) * NSEQ + s] = hv;
    });
}

// ---------------- O projection + residual ----------------
__global__ __launch_bounds__(256, 3) void gemm_o_kernel(
    const f16* __restrict__ oc, const f16* __restrict__ woT,
    const float* __restrict__ xin, float* __restrict__ xmid) {
  int mt = blockIdx.y, nt = blockIdx.x;
  int tid = threadIdx.x, lane = tid & 63, wave = tid >> 6;
  int kc = lane & 7, rs = lane >> 3;
  int kcs = (kc ^ rs) * 8;
  const f16 *a[4], *b[4];
#pragma unroll
  for (int i = 0; i < 4; i++) {
    int row = i * 32 + wave * 8 + rs;
    a[i] = oc + (size_t)(mt * 128 + row) * DMODEL + kcs;
    b[i] = woT + (size_t)(nt * 128 + row) * DMODEL + kcs;
  }
  int mB = mt * 128, nB = nt * 128;
  gemm128(a[0], a[1], a[2], a[3], b[0], b[1], b[2], b[3], DMODEL,
    [&](int r, int c, float v) {
      size_t idx = (size_t)(mB + r) * DMODEL + nB + c;
      xmid[idx] = xin[idx] + v;
    });
}

// ---------------- MoE expert GEMM 1: h -> gelu(h*w1+b1) ----------------
__global__ __launch_bounds__(256, 3) void gemm_moe1_kernel(
    const f16* __restrict__ hM, const f16* __restrict__ w1T, const float* __restrict__ b1,
    const int* __restrict__ cnt, const int* __restrict__ base, const int* __restrict__ list,
    f16* __restrict__ hid) {
  int e = blockIdx.z, mt = blockIdx.y, nt = blockIdx.x;
  int c_e = cnt[e];
  if (mt * 128 >= c_e) return;
  int tid = threadIdx.x, lane = tid & 63, wave = tid >> 6;
  int kc = lane & 7, rs = lane >> 3;
  int kcs = (kc ^ rs) * 8;
  const f16 *a[4], *b[4];
#pragma unroll
  for (int i = 0; i < 4; i++) {
    int row = i * 32 + wave * 8 + rs;
    int rr = mt * 128 + row; rr = rr < c_e ? rr : c_e - 1;
    int tok = list[e * NTOK + rr];
    a[i] = hM + (size_t)tok * DMODEL + kcs;
    b[i] = w1T + ((size_t)e * DFFN + nt * 128 + row) * DMODEL + kcs;
  }
  int rowBase = base[e] + mt * 128, nB = nt * 128, mLoc = mt * 128;
  gemm128(a[0], a[1], a[2], a[3], b[0], b[1], b[2], b[3], DMODEL,
    [&](int r, int c, float v) {
      if (mLoc + r < c_e) {
        float v2 = v + b1[e * DFFN + nB + c];
        float u = 1.5957691216057308f * (v2 + 0.044715f * v2 * v2 * v2); // 2*0.79788456*
        float th = 1.f - 2.f / (__expf(u) + 1.f);                        // tanh
        hid[(size_t)(rowBase + r) * DFFN + nB + c] = (f16)(0.5f * v2 * (1.f + th));
      }
    });
}

// ---------------- MoE expert GEMM 2: hid*w2+b2 -> y (split-K x2) ----------
__global__ __launch_bounds__(256, 3) void gemm_moe2_kernel(
    const f16* __restrict__ hid, const f16* __restrict__ w2T, const float* __restrict__ b2,
    const int* __restrict__ cnt, const int* __restrict__ base,
    float* __restrict__ y, float* __restrict__ y2) {
  int z = blockIdx.z, e = z >> 1, kh = z & 1;
  int mt = blockIdx.y, nt = blockIdx.x;
  int c_e = cnt[e];
  if (mt * 128 >= c_e) return;
  int tid = threadIdx.x, lane = tid & 63, wave = tid >> 6;
  int kc = lane & 7, rs = lane >> 3;
  int kcs = (kc ^ rs) * 8 + kh * 2048;
  int bse = base[e];
  const f16 *a[4], *b[4];
#pragma unroll
  for (int i = 0; i < 4; i++) {
    int row = i * 32 + wave * 8 + rs;
    int rr = mt * 128 + row; rr = rr < c_e ? rr : c_e - 1;
    a[i] = hid + (size_t)(bse + rr) * DFFN + kcs;
    b[i] = w2T + ((size_t)e * DMODEL + nt * 128 + row) * DFFN + kcs;
  }
  int nB = nt * 128, mLoc = mt * 128;
  float* yo = kh ? y2 : y;
  gemm128(a[0], a[1], a[2], a[3], b[0], b[1], b[2], b[3], 2048,
    [&](int r, int c, float v) {
      if (mLoc + r < c_e) {
        float bias = kh ? 0.f : b2[e * DMODEL + nB + c];
        yo[(size_t)(bse + mLoc + r) * DMODEL + nB + c] = v + bias;
      }
    });
}

// ---------------- flash attention (causal + key mask) ----------------
// R8: triangular fold — block (bh, qy) handles q-tiles qy AND 31-qy, so
// every block does exactly 33 K-tile steps (uniform makespan; was 1..32).
// Grid (32,16), 512 blocks. bh on blockIdx.x keeps head->XCD locality.
__global__ __launch_bounds__(256, 4) void attn_kernel(
    const f16* __restrict__ qb, const f16* __restrict__ kb, const f16* __restrict__ vtb,
    const int* __restrict__ amask, f16* __restrict__ oc) {
  int bh = blockIdx.x, qy = blockIdx.y;
  int bI = bh >> 4, h = bh & 15;
  int tid = threadIdx.x, lane = tid & 63, wave = tid >> 6;
  int q4 = lane >> 4, l15 = lane & 15;
  int kc = lane & 7, rs = lane >> 3;

  __shared__ __align__(16) f16 sQ[64 * 64];
  __shared__ __align__(16) f16 sK[64 * 64];
  __shared__ __align__(16) f16 sVT[64 * 64];
  __shared__ __align__(16) f16 sP[4][16 * 64];
  __shared__ int sMask[64];

  const f16* qBH = qb + (size_t)bh * NSEQ * HDIM;
  const f16* kBH = kb + (size_t)bh * NSEQ * HDIM;
  const f16* vBH = vtb + (size_t)bh * HDIM * NSEQ;
  f16* sPw = sP[wave];
  f32x4 zero = {0.f, 0.f, 0.f, 0.f};

  for (int pass = 0; pass < 2; pass++) {
    int qt = pass ? (31 - qy) : qy;
    int qbase = qt * 64;

    __syncthreads();  // prior pass done reading sQ before overwrite
#pragma unroll
    for (int i = 0; i < 2; i++) {
      int row = i * 32 + wave * 8 + rs;  // 0..63
      ldsAsync16(qBH + (size_t)(qbase + row) * HDIM + kc * 8, &sQ[(i * 4 + wave) * 512]);
    }

    f32x4 accO[4];
    float mrow[4], lrow[4];
#pragma unroll
    for (int j = 0; j < 4; j++) { accO[j] = zero; mrow[j] = -3.0e38f; lrow[j] = 0.f; }

    for (int kt = 0; kt <= qt; kt++) {
      int kb0 = kt * 64;
      bool diag = (kt == qt);
      __syncthreads();
#pragma unroll
      for (int i = 0; i < 2; i++) {
        int row = i * 32 + wave * 8 + rs;  // 0..63
        ldsAsync16(kBH + (size_t)(kb0 + row) * HDIM + kc * 8, &sK[(i * 4 + wave) * 512]);
        ldsAsync16(vBH + (size_t)row * NSEQ + kb0 + kc * 8, &sVT[(i * 4 + wave) * 512]);
      }
      if (tid < 64) sMask[tid] = amask[bI * NSEQ + kb0 + tid];
      __syncthreads();

      f32x4 accS[4];
#pragma unroll
      for (int j = 0; j < 4; j++) accS[j] = zero;
#pragma unroll
      for (int kk = 0; kk < 2; kk++) {
        f16x8 af = *(const f16x8*)&sQ[(wave * 16 + l15) * 64 + kk * 32 + q4 * 8];
        f16x8 bf[4];
#pragma unroll
        for (int nj = 0; nj < 4; nj++)
          bf[nj] = *(const f16x8*)&sK[(nj * 16 + l15) * 64 + kk * 32 + q4 * 8];
#pragma unroll
        for (int nj = 0; nj < 4; nj++)
          accS[nj] = __builtin_amdgcn_mfma_f32_16x16x32_f16(af, bf[nj], accS[nj], 0, 0, 0);
      }
      bool mok[4];
      int gk[4];
#pragma unroll
      for (int nj = 0; nj < 4; nj++) {
        gk[nj] = nj * 16 + l15;
        mok[nj] = sMask[gk[nj]] > 0;
      }
#pragma unroll
      for (int r = 0; r < 4; r++) {
        int lq = wave * 16 + q4 * 4 + r;  // local q row 0..63; global gq = qbase+lq
        float rm = -3.0e38f;
#pragma unroll
        for (int nj = 0; nj < 4; nj++) {
          float s = accS[nj][r] * 0.125f;
          bool ok = mok[nj] && (!diag || gk[nj] <= lq);
          s = ok ? s : -1.0e9f;
          accS[nj][r] = s;
          rm = fmaxf(rm, s);
        }
#pragma unroll
        for (int o = 1; o < 16; o <<= 1) rm = fmaxf(rm, __shfl_xor(rm, o));
        float mold = mrow[r];
        float mnew = fmaxf(mold, rm);
        float alpha = __expf(mold - mnew);
        float rsum = 0.f;
#pragma unroll
        for (int nj = 0; nj < 4; nj++) {
          float p = __expf(accS[nj][r] - mnew);
          rsum += p;
          sPw[(q4 * 4 + r) * 64 + nj * 16 + l15] = (f16)p;
        }
#pragma unroll
        for (int o = 1; o < 16; o <<= 1) rsum += __shfl_xor(rsum, o);
        lrow[r] = lrow[r] * alpha + rsum;
        mrow[r] = mnew;
#pragma unroll
        for (int dj = 0; dj < 4; dj++) accO[dj][r] *= alpha;
      }
      // PV (sP is per-wave private; compiler's lgkmcnt covers write->read)
#pragma unroll
      for (int kk = 0; kk < 2; kk++) {
        f16x8 pf = *(const f16x8*)&sPw[l15 * 64 + kk * 32 + q4 * 8];
        f16x8 vf[4];
#pragma unroll
        for (int dj = 0; dj < 4; dj++)
          vf[dj] = *(const f16x8*)&sVT[(dj * 16 + l15) * 64 + kk * 32 + q4 * 8];
#pragma unroll
        for (int dj = 0; dj < 4; dj++)
          accO[dj] = __builtin_amdgcn_mfma_f32_16x16x32_f16(pf, vf[dj], accO[dj], 0, 0, 0);
      }
    }
    // epilogue: divide by l, scatter to o_concat[token][h*64+d]
#pragma unroll
    for (int r = 0; r < 4; r++) {
      float inv = 1.f / lrow[r];
      int s = qbase + wave * 16 + q4 * 4 + r;
      size_t rowoff = ((size_t)bI * NSEQ + s) * DMODEL + h * HDIM;
#pragma unroll
      for (int dj = 0; dj < 4; dj++)
        oc[rowoff + dj * 16 + l15] = (f16)(accO[dj][r] * inv);
    }
  }
}

// ---------------- router: wave-per-token, NO global atomics ----------------
__global__ __launch_bounds__(256) void router_kernel(
    const float* __restrict__ xmid, const float* __restrict__ normw,
    const float* __restrict__ rw, int2* __restrict__ metaE,
    float2* __restrict__ metaS, float* __restrict__ blockpsum) {
  int wave = threadIdx.x >> 6, lane = threadIdx.x & 63;
  int t = blockIdx.x * 4 + wave;
  __shared__ float sprob[4][8];

  const float4* xr = (const float4*)(xmid + (size_t)t * DMODEL);
  const float4* wr = (const float4*)normw;
  float4 v[4];
  float ss = 0.f;
#pragma unroll
  for (int i = 0; i < 4; i++) {
    v[i] = xr[lane * 4 + i];
    ss += v[i].x * v[i].x + v[i].y * v[i].y + v[i].z * v[i].z + v[i].w * v[i].w;
  }
#pragma unroll
  for (int o = 32; o > 0; o >>= 1) ss += __shfl_xor(ss, o);
  float rstd = rsqrtf(ss / (float)DMODEL + 1e-6f);

  float part[8] = {0, 0, 0, 0, 0, 0, 0, 0};
#pragma unroll
  for (int i = 0; i < 4; i++) {
    float4 wv = wr[lane * 4 + i];
    float hv[4] = {v[i].x * rstd * wv.x, v[i].y * rstd * wv.y,
                   v[i].z * rstd * wv.z, v[i].w * rstd * wv.w};
#pragma unroll
    for (int j = 0; j < 4; j++) {
      int row = lane * 16 + i * 4 + j;
      const float4* rr = (const float4*)(rw + (size_t)row * NEXP);
      float4 a = rr[0], b = rr[1];
      part[0] += hv[j] * a.x; part[1] += hv[j] * a.y;
      part[2] += hv[j] * a.z; part[3] += hv[j] * a.w;
      part[4] += hv[j] * b.x; part[5] += hv[j] * b.y;
      part[6] += hv[j] * b.z; part[7] += hv[j] * b.w;
    }
  }
#pragma unroll
  for (int o = 1; o < 64; o <<= 1)
#pragma unroll
    for (int e = 0; e < 8; e++) part[e] += __shfl_xor(part[e], o);

  if (lane == 0) {
    float mx = -3.0e38f;
#pragma unroll
    for (int e = 0; e < 8; e++) mx = fmaxf(mx, part[e]);
    float probs[8], sum = 0.f;
#pragma unroll
    for (int e = 0; e < 8; e++) { probs[e] = __expf(part[e] - mx); sum += probs[e]; }
    float inv = 1.f / sum;
#pragma unroll
    for (int e = 0; e < 8; e++) { probs[e] *= inv; sprob[wave][e] = probs[e]; }
    int e0 = 0;
#pragma unroll
    for (int e = 1; e < 8; e++) if (part[e] > part[e0]) e0 = e;
    int e1 = (e0 == 0) ? 1 : 0;
#pragma unroll
    for (int e = 0; e < 8; e++) if (e != e0 && part[e] > part[e1]) e1 = e;
    metaE[t] = make_int2(e0, e1);
    metaS[t] = make_float2(probs[e0], probs[e1]);
  }
  __syncthreads();
  if (threadIdx.x < 8)
    blockpsum[blockIdx.x * 8 + threadIdx.x] =
        sprob[0][threadIdx.x] + sprob[1][threadIdx.x] +
        sprob[2][threadIdx.x] + sprob[3][threadIdx.x];
}

// ---------------- scatter: one block per expert, deterministic prefix sum ----
__global__ __launch_bounds__(256) void scatter_kernel(
    const int2* __restrict__ metaE, int* __restrict__ list,
    int* __restrict__ metaP, int* __restrict__ cnt) {
  int e = blockIdx.x;
  int tid = threadIdx.x, lane = tid & 63, w = tid >> 6;
  __shared__ int wsum[4];
  __shared__ int sbase;
  if (tid == 0) sbase = 0;
  __syncthreads();
  for (int c = 0; c < NTOK; c += 256) {
    int tok = c + tid;
    int2 me = metaE[tok];
    bool m0 = (me.x == e), m1 = (me.y == e);
    bool m = m0 || m1;
    unsigned long long mask = __ballot(m);
    int wpre = __popcll(mask & ((1ull << lane) - 1ull));
    if (lane == 0) wsum[w] = __popcll(mask);
    __syncthreads();
    int base0 = sbase;
    int pre = wpre;
    for (int i = 0; i < w; i++) pre += wsum[i];
    int tot = wsum[0] + wsum[1] + wsum[2] + wsum[3];
    if (m) {
      int pos = base0 + pre;
      list[e * NTOK + base0 + pre] = tok;
      metaP[tok * 2 + (m0 ? 0 : 1)] = pos;
    }
    __syncthreads();
    if (tid == 0) sbase = base0 + tot;
  }
  __syncthreads();
  if (tid == 0) cnt[e] = sbase;
}

// ---------------- finalize: base offsets + balancing loss + counts ----------
__global__ __launch_bounds__(256) void finalize_kernel(
    const int* __restrict__ cnt, const float* __restrict__ blockpsum,
    int* __restrict__ base, float* __restrict__ out_tail) {
  int tid = threadIdx.x;
  int e = tid & 7, slot = tid >> 3;  // 32 slots per expert
  float acc = 0.f;
  for (int i = slot; i < 1024; i += 32) acc += blockpsum[i * 8 + e];
  __shared__ float red[256];
  red[tid] = acc;
  __syncthreads();
  for (int s = 128; s >= 8; s >>= 1) {
    if (tid < s) red[tid] += red[tid + s];
    __syncthreads();
  }
  if (tid == 0) {
    int b = 0;
#pragma unroll
    for (int i = 0; i < 8; i++) { base[i] = b; b += cnt[i]; }
    base[8] = b;
    float loss = 0.f;
#pragma unroll
    for (int i = 0; i < 8; i++)
      loss += ((float)cnt[i] / (float)NPAIR) * (red[i] / (float)NTOK);
    out_tail[0] = loss * (float)NEXP;
#pragma unroll
    for (int i = 0; i < 8; i++) out_tail[1 + i] = (float)cnt[i];
  }
}

// ---------------- final combine (sums split-K halves) ----------------
__global__ void combine_kernel(const float* __restrict__ xmid, const float* __restrict__ yv,
                               const float* __restrict__ yv2,
                               const int2* __restrict__ metaE, const int* __restrict__ metaP,
                               const float2* __restrict__ metaS,
                               const int* __restrict__ base, float* __restrict__ out) {
  int t = blockIdx.x, tid = threadIdx.x;
  int2 me = metaE[t];
  float2 sc = metaS[t];
  size_t s0 = (size_t)(base[me.x] + metaP[t * 2 + 0]) * DMODEL;
  size_t s1 = (size_t)(base[me.y] + metaP[t * 2 + 1]) * DMODEL;
  float4 a = ((const float4*)(xmid + (size_t)t * DMODEL))[tid];
  float4 y0a = ((const float4*)(yv + s0))[tid];
  float4 y0b = ((const float4*)(yv2 + s0))[tid];
  float4 y1a = ((const float4*)(yv + s1))[tid];
  float4 y1b = ((const float4*)(yv2 + s1))[tid];
  float4 o;
  o.x = a.x + sc.x * (y0a.x + y0b.x) + sc.y * (y1a.x + y1b.x);
  o.y = a.y + sc.x * (y0a.y + y0b.y) + sc.y * (y1a.y + y1b.y);
  o.z = a.z + sc.x * (y0a.z + y0b.z) + sc.y * (y1a.z + y1b.z);
  o.w = a.w + sc.x * (y0a.w + y0b.w) + sc.y * (y1a.w + y1b.w);
  ((float4*)(out + (size_t)t * DMODEL))[tid] = o;
}

// ---------------------------------------------------------------------------
extern "C" void kernel_launch(void* const* d_in, const int* in_sizes, int n_in,
                              void* d_out, int out_size, void* d_ws, size_t ws_size,
                              hipStream_t stream) {
  (void)in_sizes; (void)n_in; (void)out_size; (void)ws_size;
  const float* x    = (const float*)d_in[0];
  const int*   am   = (const int*)d_in[1];
  const float* anw  = (const float*)d_in[2];
  const float* wq   = (const float*)d_in[3];
  const float* wk   = (const float*)d_in[4];
  const float* wv   = (const float*)d_in[5];
  const float* wo   = (const float*)d_in[6];
  const float* mnw  = (const float*)d_in[7];
  const float* rw   = (const float*)d_in[8];
  const float* w1   = (const float*)d_in[9];
  const float* b1   = (const float*)d_in[10];
  const float* w2   = (const float*)d_in[11];
  const float* b2   = (const float*)d_in[12];
  float* out = (float*)d_out;
  char* ws = (char*)d_ws;

  f16* wqkvT = (f16*)(ws + OFF_WQKVT);
  f16* woT   = (f16*)(ws + OFF_WOT);
  f16* w1T   = (f16*)(ws + OFF_W1T);
  f16* w2T   = (f16*)(ws + OFF_W2T);
  f16* hattn = (f16*)(ws + OFF_HATTN);
  f16* qb    = (f16*)(ws + OFF_Q);
  f16* kb    = (f16*)(ws + OFF_K);
  f16* vtb   = (f16*)(ws + OFF_VT);
  f16* oc    = (f16*)(ws + OFF_OC);
  float* xmid = (float*)(ws + OFF_XMID);
  f16* hmlp  = (f16*)(ws + OFF_HMLP);
  f16* hid   = (f16*)(ws + OFF_HID);
  float* y   = (float*)(ws + OFF_Y);
  float* y2  = (float*)(ws + OFF_Y2);
  int* list  = (int*)(ws + OFF_LIST);
  int2* metaE = (int2*)(ws + OFF_METAE);
  int* metaP  = (int*)(ws + OFF_METAP);
  float2* metaS = (float2*)(ws + OFF_METAS);
  float* bpsum = (float*)(ws + OFF_BPSUM);
  int* cnt   = (int*)(ws + OFF_CNT);
  int* base  = (int*)(ws + OFF_BASE);

  transpose_cast_kernel<<<dim3(16, 16, 1), 256, 0, stream>>>(wq, wqkvT, 1024, 1024);
  transpose_cast_kernel<<<dim3(16, 16, 1), 256, 0, stream>>>(wk, wqkvT + 1024 * 1024, 1024, 1024);
  transpose_cast_kernel<<<dim3(16, 16, 1), 256, 0, stream>>>(wv, wqkvT + 2 * 1024 * 1024, 1024, 1024);
  transpose_cast_kernel<<<dim3(16, 16, 1), 256, 0, stream>>>(wo, woT, 1024, 1024);
  transpose_cast_kernel<<<dim3(64, 16, 8), 256, 0, stream>>>(w1, w1T, 1024, 4096);
  transpose_cast_kernel<<<dim3(16, 64, 8), 256, 0, stream>>>(w2, w2T, 4096, 1024);

  rmsnorm_kernel<<<NTOK, 256, 0, stream>>>(x, anw, hattn);
  gemm_qkv_kernel<<<dim3(24, 32), 256, 0, stream>>>(hattn, wqkvT, qb, kb, vtb);
  attn_kernel<<<dim3(32, 16), 256, 0, stream>>>(qb, kb, vtb, am, oc);
  gemm_o_kernel<<<dim3(8, 32), 256, 0, stream>>>(oc, woT, x, xmid);
  rmsnorm_kernel<<<NTOK, 256, 0, stream>>>(xmid, mnw, hmlp);
  router_kernel<<<1024, 256, 0, stream>>>(xmid, mnw, rw, metaE, metaS, bpsum);
  scatter_kernel<<<8, 256, 0, stream>>>(metaE, list, metaP, cnt);
  finalize_kernel<<<1, 256, 0, stream>>>(cnt, bpsum, base, out + (size_t)NTOK * DMODEL);
  gemm_moe1_kernel<<<dim3(32, 32, 8), 256, 0, stream>>>(hmlp, w1T, b1, cnt, base, list, hid);
  gemm_moe2_kernel<<<dim3(8, 32, 16), 256, 0, stream>>>(hid, w2T, b2, cnt, base, y, y2);
  combine_kernel<<<NTOK, 256, 0, stream>>>(xmid, y, y2, metaE, metaP, metaS, base, out);
}